// Round 3
// baseline (2684.430 us; speedup 1.0000x reference)
//
#include <hip/hip_runtime.h>
#include <math.h>

// GNN: GatedGraphConv(4 steps) + BN/ReLU + mean-pool + MLP head. fp32, decoupled.
// C_i = ggc_w[i] @ gru_wih^T precomputed, so per step:
//   s = gather_sum(h[src] -> dst)   (k_agg, CSR, latency-optimized)
//   GRU(s@C_i, h@Whh^T)             (k_gemm_gru, LDS tile, quad-k weights)
// k_gemm_gru writes hout in-place over its own s rows (block-local) -> 3 buffers.

#define EPSV 1e-5f

__device__ __forceinline__ float fsig(float x){
  return 1.0f/(1.0f+__expf(-x));
}
__device__ __forceinline__ float ftanh(float x){
  float ax = fabsf(x);
  float e = __expf(-2.0f*ax);
  float r = (1.0f-e)/(1.0f+e);
  return copysignf(r, x);
}

__global__ void k_zero(float* __restrict__ p, int n){
  int i = blockIdx.x*256+threadIdx.x;
  if (i<n) p[i]=0.0f;
}

// ---- fused prep: WtIn quad, HW quad, CW quad (=ggc@wih^T), W1cT ----
// Quad layouts pair k in groups of 4 for float4 loads in the GEMM inner loops.
//   Wq  [(k>>2)*512  + j*4 + (k&3)] = Win[j*128+k]
//   HWq [(k>>2)*1536 + c*4 + (k&3)] = whh[c*128+k]          (c = gate*128+j)
//   CWq [s*49152 + (k>>2)*1536 + c*4 + (k&3)] = sum_m ggc[s][k][m]*wih[c][m]
__global__ void k_prep(const float* __restrict__ Win, float* __restrict__ Wq,
                       const float* __restrict__ whh, float* __restrict__ HWq,
                       const float* __restrict__ ggc, const float* __restrict__ wih,
                       float* __restrict__ CWq,
                       const float* __restrict__ W1, float* __restrict__ W1cT){
  int i = blockIdx.x*256+threadIdx.x;
  if (i < 16384){
    int k=i>>7, j=i&127;
    Wq[(k>>2)*512 + j*4 + (k&3)] = Win[j*128+k];
  } else if (i < 65536){
    int r=i-16384; int k=r/384, c=r%384;
    HWq[(k>>2)*1536 + c*4 + (k&3)] = whh[c*128+k];
  } else if (i < 262144){
    int r=i-65536; int s=r/49152; int r2=r%49152; int k=r2/384; int c=r2%384;
    const float* g = ggc + s*16384 + k*128;
    const float* w = wih + c*128;
    float acc=0.f;
    for (int m=0;m<128;m++) acc += g[m]*w[m];
    CWq[s*49152 + (k>>2)*1536 + c*4 + (k&3)] = acc;
  } else if (i < 278528){
    int r=i-262144; int j=r>>7, o=r&127;
    W1cT[j*128+o] = W1[o*256+j] + W1[o*256+128+j];
  }
}

// t = x @ W_in^T + b_in, fused BN1 column stat partials (64-way)
__global__ __launch_bounds__(256,2) void k_gemm_in(
    const float* __restrict__ x, const float* __restrict__ Wq, const float* __restrict__ bin,
    float* __restrict__ X, float* __restrict__ sumP, float* __restrict__ sqP, int N)
{
  __shared__ __align__(16) float xl[32][128];
  __shared__ float red[2][128];
  int t=threadIdx.x;
  int nbase = blockIdx.x*32;
  for (int it=0; it<4; ++it){
    int f4 = it*256+t;            // 1024 float4s = 32x128 floats
    int n = f4>>5; int k=(f4&31)*4;
    int gn=nbase+n;
    float4 v = make_float4(0.f,0.f,0.f,0.f);
    if (gn<N) v = *(const float4*)&x[(size_t)gn*128+k];
    *(float4*)&xl[n][k]=v;
  }
  __syncthreads();
  int j=t&127, half=t>>7, nb=half*16;
  float acc[16];
  #pragma unroll
  for (int q=0;q<16;q++) acc[q]=0.f;
  for (int k=0;k<128;k+=4){
    float4 w = *(const float4*)&Wq[(k>>2)*512 + j*4];
    #pragma unroll
    for (int q=0;q<16;q++){
      float4 xv = *(const float4*)&xl[nb+q][k];
      acc[q] += xv.x*w.x + xv.y*w.y + xv.z*w.z + xv.w*w.w;
    }
  }
  float bv = bin[j];
  float ts=0.f, tq=0.f;
  #pragma unroll
  for (int q=0;q<16;q++){
    int n=nbase+nb+q;
    if (n<N){
      float tv=acc[q]+bv;
      X[(size_t)n*128+j]=tv;
      ts+=tv; tq+=tv*tv;
    }
  }
  int p = (blockIdx.x&63)*128+j;
  red[half][j]=ts; __syncthreads();
  if (half==0) atomicAdd(&sumP[p], red[0][j]+red[1][j]);
  __syncthreads();
  red[half][j]=tq; __syncthreads();
  if (half==0) atomicAdd(&sqP[p], red[0][j]+red[1][j]);
}

// reduce partials -> BN scale/shift
__global__ void k_bn_fin(const float* __restrict__ sumP, const float* __restrict__ sqP, int P, float invcnt,
                         const float* __restrict__ g, const float* __restrict__ b,
                         float* __restrict__ sc, float* __restrict__ sh){
  int j = threadIdx.x;
  if (j>=128) return;
  float s=0.f,q=0.f;
  for (int p=0;p<P;p++){ s+=sumP[p*128+j]; q+=sqP[p*128+j]; }
  float mu = s*invcnt;
  float var = fmaxf(q*invcnt - mu*mu, 0.f);
  float scale = g[j]*rsqrtf(var+EPSV);
  sc[j]=scale; sh[j]=b[j]-mu*scale;
}

// h0 = relu(t*sc+sh)
__global__ void k_apply_bn1(const float4* __restrict__ X, const float* __restrict__ sc,
                            const float* __restrict__ sh, float4* __restrict__ h0, int total4){
  int i = blockIdx.x*256+threadIdx.x;
  if (i>=total4) return;
  float4 t = X[i];
  int j0 = (i*4)&127;
  float4 s = *(const float4*)&sc[j0];
  float4 b = *(const float4*)&sh[j0];
  float4 o;
  o.x = fmaxf(t.x*s.x+b.x, 0.f);
  o.y = fmaxf(t.y*s.y+b.y, 0.f);
  o.z = fmaxf(t.z*s.z+b.z, 0.f);
  o.w = fmaxf(t.w*s.w+b.w, 0.f);
  h0[i]=o;
}

// ---- CSR build (rows = dst, cols = src) ----
__global__ void k_hist(const int* __restrict__ dst, int* __restrict__ deg, int E){
  int e = blockIdx.x*256+threadIdx.x;
  if (e<E) atomicAdd(&deg[dst[e]], 1);
}
__global__ void k_scan1(const int* __restrict__ deg, int* __restrict__ rowptr, int* __restrict__ bsum, int N){
  __shared__ int tmp[256];
  int t=threadIdx.x; int n=blockIdx.x*256+t;
  int v = (n<N)?deg[n]:0;
  tmp[t]=v;
  __syncthreads();
  for (int o=1;o<256;o<<=1){
    int add = (t>=o)? tmp[t-o] : 0;
    __syncthreads();
    tmp[t]+=add;
    __syncthreads();
  }
  if (n<N) rowptr[n+1]=tmp[t];
  if (t==255) bsum[blockIdx.x]=tmp[255];
}
// parallel scan of block sums (nb <= 512) -> exclusive
__global__ void k_scan2(int* bsum, int nb, int* rowptr){
  __shared__ int tmp[512];
  int t=threadIdx.x;
  int v = (t<nb)? bsum[t] : 0;
  tmp[t]=v; __syncthreads();
  for (int o=1;o<512;o<<=1){
    int add = (t>=o)? tmp[t-o] : 0;
    __syncthreads();
    tmp[t]+=add;
    __syncthreads();
  }
  if (t<nb) bsum[t]=tmp[t]-v;
  if (t==0) rowptr[0]=0;
}
__global__ void k_scan3(int* rowptr, const int* __restrict__ bsum, int N){
  int n = blockIdx.x*256+threadIdx.x;
  if (n<N) rowptr[n+1] += bsum[blockIdx.x];
}
// fill via atomicSub on deg (consumes deg; no cur array)
__global__ void k_fill(const int* __restrict__ ei, int* __restrict__ deg,
                       const int* __restrict__ rowptr, int* __restrict__ col, int E){
  int e = blockIdx.x*256+threadIdx.x;
  if (e<E){
    int d = ei[E+e];
    int old = atomicSub(&deg[d],1);
    col[rowptr[d] + old - 1] = ei[e];
  }
}

// s[n] = sum_{e in row n} h[col[e]]  — one wave per node, 4 rows in flight
__global__ __launch_bounds__(256,8) void k_agg(
    const float* __restrict__ h, float* __restrict__ s,
    const int* __restrict__ rowptr, const int* __restrict__ col, int N)
{
  int wave = (blockIdx.x*256+threadIdx.x)>>6;
  int lane = threadIdx.x&63;
  if (wave>=N) return;
  int e = rowptr[wave], e1 = rowptr[wave+1];
  float2 a0=make_float2(0.f,0.f), a1=a0, a2=a0, a3=a0;
  for (; e+3<e1; e+=4){
    int c0=col[e],c1=col[e+1],c2=col[e+2],c3=col[e+3];
    float2 v0 = *(const float2*)&h[(size_t)c0*128+lane*2];
    float2 v1 = *(const float2*)&h[(size_t)c1*128+lane*2];
    float2 v2 = *(const float2*)&h[(size_t)c2*128+lane*2];
    float2 v3 = *(const float2*)&h[(size_t)c3*128+lane*2];
    a0.x+=v0.x; a0.y+=v0.y; a1.x+=v1.x; a1.y+=v1.y;
    a2.x+=v2.x; a2.y+=v2.y; a3.x+=v3.x; a3.y+=v3.y;
  }
  for (; e<e1; e++){
    int c0=col[e];
    float2 v0 = *(const float2*)&h[(size_t)c0*128+lane*2];
    a0.x+=v0.x; a0.y+=v0.y;
  }
  float2 r;
  r.x=(a0.x+a1.x)+(a2.x+a3.x);
  r.y=(a0.y+a1.y)+(a2.y+a3.y);
  *(float2*)&s[(size_t)wave*128+lane*2]=r;
}

// GEMM (gi = s@C, gh = h@Whh^T) + GRU update. 32-node tile staged in LDS.
// hout may alias s (block writes only its own staged rows). Optional fused
// column stats for BN2 (last step).
__global__ __launch_bounds__(256,2) void k_gemm_gru(
    const float* s, const float* __restrict__ hin, float* hout,
    const float* __restrict__ CW, const float* __restrict__ HW,
    const float* __restrict__ bih, const float* __restrict__ bhh, int N,
    float* __restrict__ sumP, float* __restrict__ sqP)
{
  __shared__ __align__(16) float sh[32][2][128];
  int t = threadIdx.x;
  int nbase = blockIdx.x*32;
  for (int it=0; it<8; ++it){
    int f4 = it*256 + t;              // 2048 float4s = 32*2*128 floats
    int flat = f4*4;
    int n = flat>>8; int rem = flat&255; int which = rem>>7; int k = rem&127;
    int gn = nbase+n;
    float4 v = make_float4(0.f,0.f,0.f,0.f);
    if (gn<N){
      const float* src = which ? &hin[(size_t)gn*128+k] : &s[(size_t)gn*128+k];
      v = *(const float4*)src;
    }
    *(float4*)&sh[n][which][k] = v;
  }
  __syncthreads();
  int j=t&127, half=t>>7, nb=half*16;
  float air[16],aiz[16],ain[16],ahr[16],ahz[16],ahn[16];
  #pragma unroll
  for (int q=0;q<16;q++){ air[q]=0.f;aiz[q]=0.f;ain[q]=0.f;ahr[q]=0.f;ahz[q]=0.f;ahn[q]=0.f; }
  for (int k=0;k<128;k+=4){
    const float* cwb = &CW[(k>>2)*1536];
    const float* hwb = &HW[(k>>2)*1536];
    float4 wir = *(const float4*)&cwb[j*4];
    float4 wiz = *(const float4*)&cwb[512 + j*4];
    float4 win = *(const float4*)&cwb[1024 + j*4];
    float4 whr = *(const float4*)&hwb[j*4];
    float4 whz = *(const float4*)&hwb[512 + j*4];
    float4 whn = *(const float4*)&hwb[1024 + j*4];
    #pragma unroll
    for (int q=0;q<16;q++){
      float4 sv = *(const float4*)&sh[nb+q][0][k];
      float4 hv = *(const float4*)&sh[nb+q][1][k];
      air[q] += sv.x*wir.x + sv.y*wir.y + sv.z*wir.z + sv.w*wir.w;
      aiz[q] += sv.x*wiz.x + sv.y*wiz.y + sv.z*wiz.z + sv.w*wiz.w;
      ain[q] += sv.x*win.x + sv.y*win.y + sv.z*win.z + sv.w*win.w;
      ahr[q] += hv.x*whr.x + hv.y*whr.y + hv.z*whr.z + hv.w*whr.w;
      ahz[q] += hv.x*whz.x + hv.y*whz.y + hv.z*whz.z + hv.w*whz.w;
      ahn[q] += hv.x*whn.x + hv.y*whn.y + hv.z*whn.z + hv.w*whn.w;
    }
  }
  float br=bih[j], bz=bih[128+j], bn_=bih[256+j];
  float cr=bhh[j], cz=bhh[128+j], cn=bhh[256+j];
  float ts=0.f, tq=0.f;
  #pragma unroll
  for (int q=0;q<16;q++){
    int n = nbase+nb+q;
    if (n<N){
      float r = fsig((air[q]+br) + (ahr[q]+cr));
      float z = fsig((aiz[q]+bz) + (ahz[q]+cz));
      float nn = ftanh((ain[q]+bn_) + r*(ahn[q]+cn));
      float hold = sh[nb+q][1][j];
      float hv2 = (1.f-z)*nn + z*hold;
      hout[(size_t)n*128+j]=hv2;
      ts+=hv2; tq+=hv2*hv2;
    }
  }
  if (sumP){
    float* red = &sh[0][0][0];      // reuse staged LDS (all reads done)
    __syncthreads();
    red[half*128+j]=ts; __syncthreads();
    if (half==0) atomicAdd(&sumP[(blockIdx.x&63)*128+j], red[j]+red[128+j]);
    __syncthreads();
    red[half*128+j]=tq; __syncthreads();
    if (half==0) atomicAdd(&sqP[(blockIdx.x&63)*128+j], red[j]+red[128+j]);
  }
}

// hf = relu(bn2(h)+skip), run-length pooled (batch sorted) + fused node count
__global__ void k_bn2_pool(const float* __restrict__ hfin, const float* __restrict__ h0,
                           const int* __restrict__ batch, const float* __restrict__ sc,
                           const float* __restrict__ sh, float* __restrict__ pool,
                           float* __restrict__ cntf, int N){
  int t=threadIdx.x, j=t&127, half=t>>7;
  int n0 = blockIdx.x*256 + half*128;
  float scv=sc[j], shv=sh[j];
  int curg=-1; float acc=0.f, cacc=0.f;
  for (int r=0;r<128;r++){
    int n=n0+r; if (n>=N) break;
    int g = batch[n];
    float v = fmaxf(hfin[(size_t)n*128+j]*scv+shv + h0[(size_t)n*128+j], 0.f);
    if (g!=curg){
      if (curg>=0){
        atomicAdd(&pool[curg*128+j], acc);
        if (j==0) atomicAdd(&cntf[curg], cacc);
      }
      curg=g; acc=0.f; cacc=0.f;
    }
    acc+=v; cacc+=1.f;
  }
  if (curg>=0){
    atomicAdd(&pool[curg*128+j], acc);
    if (j==0) atomicAdd(&cntf[curg], cacc);
  }
}

// t3[g][o] = b1[o] + mean[g]·W1cT[:,o]; + BN3 stat atomics
__global__ void k_head1(const float* __restrict__ pool, const float* __restrict__ cntf,
                        const float* __restrict__ W1cT, const float* __restrict__ b1,
                        float* __restrict__ t3, float* __restrict__ sum3, float* __restrict__ sq3){
  __shared__ float mean[128];
  int g=blockIdx.x, o=threadIdx.x;
  float inv = 1.0f/fmaxf(cntf[g],1.0f);
  mean[o] = pool[g*128+o]*inv;
  __syncthreads();
  float acc=0.f;
  for (int jj=0;jj<128;jj++) acc += mean[jj]*W1cT[jj*128+o];
  float v = acc + b1[o];
  t3[g*128+o]=v;
  atomicAdd(&sum3[o], v);
  atomicAdd(&sq3[o], v*v);
}

// y1 = relu(bn3(t3)); out = y1 @ W2^T + b2
__global__ void k_head2(const float* __restrict__ t3, const float* __restrict__ sc,
                        const float* __restrict__ sh, const float* __restrict__ W2,
                        const float* __restrict__ b2, float* __restrict__ out){
  __shared__ float y[128];
  int g=blockIdx.x, o=threadIdx.x;
  float v = fmaxf(t3[g*128+o]*sc[o]+sh[o], 0.f);
  y[o]=v; __syncthreads();
  if (o<2){
    float acc=b2[o];
    for (int k=0;k<128;k++) acc += y[k]*W2[o*128+k];
    out[g*2+o]=acc;
  }
}

extern "C" void kernel_launch(void* const* d_in, const int* in_sizes, int n_in,
                              void* d_out, int out_size, void* d_ws, size_t ws_size,
                              hipStream_t stream){
  (void)n_in; (void)ws_size;
  const float* x    = (const float*)d_in[0];
  const int*   ei   = (const int*)d_in[1];
  const int*   batch= (const int*)d_in[2];
  const float* W_in = (const float*)d_in[3];
  const float* b_in = (const float*)d_in[4];
  const float* bn1_g= (const float*)d_in[5];
  const float* bn1_b= (const float*)d_in[6];
  const float* ggc  = (const float*)d_in[7];
  const float* wih  = (const float*)d_in[8];
  const float* whh  = (const float*)d_in[9];
  const float* bih  = (const float*)d_in[10];
  const float* bhh  = (const float*)d_in[11];
  const float* bn2_g= (const float*)d_in[12];
  const float* bn2_b= (const float*)d_in[13];
  const float* W1   = (const float*)d_in[14];
  const float* b1   = (const float*)d_in[15];
  const float* bn3_g= (const float*)d_in[16];
  const float* bn3_b= (const float*)d_in[17];
  const float* W2   = (const float*)d_in[18];
  const float* b2   = (const float*)d_in[19];
  float* out = (float*)d_out;

  int N = in_sizes[0]/128;
  int E = in_sizes[1]/2;
  int G = out_size/2;

  char* ws = (char*)d_ws;
  size_t off=0;
  auto alloc=[&](size_t bytes)->char*{
    char* p = ws+off; off = (off+bytes+255) & ~(size_t)255; return p;
  };
  float* buf0 = (float*)alloc((size_t)N*128*4);   // t -> s1/h1 -> s3/h3
  float* h0   = (float*)alloc((size_t)N*128*4);   // skip (persist)
  float* buf2 = (float*)alloc((size_t)N*128*4);   // s2/h2 -> s4/h4
  float* CW   = (float*)alloc((size_t)4*49152*4);
  float* HW   = (float*)alloc((size_t)49152*4);
  float* Wq   = (float*)alloc((size_t)16384*4);
  float* W1cT = (float*)alloc((size_t)16384*4);
  int* rowptr = (int*)alloc((size_t)(N+1)*4);
  int* col    = (int*)alloc((size_t)E*4);
  int* bsum   = (int*)alloc((size_t)512*4);
  float* t3   = (float*)alloc((size_t)G*128*4);
  float* sc1 = (float*)alloc(512); float* sh1 = (float*)alloc(512);
  float* sc2 = (float*)alloc(512); float* sh2 = (float*)alloc(512);
  float* sc3 = (float*)alloc(512); float* sh3 = (float*)alloc(512);
  // --- zero region (contiguous) ---
  char* zstart = ws+off;
  int*   deg  = (int*)alloc((size_t)N*4);
  float* sumP1= (float*)alloc((size_t)64*128*4);
  float* sqP1 = (float*)alloc((size_t)64*128*4);
  float* sumP2= (float*)alloc((size_t)64*128*4);
  float* sqP2 = (float*)alloc((size_t)64*128*4);
  float* sum3 = (float*)alloc(512);
  float* sq3  = (float*)alloc(512);
  float* pool = (float*)alloc((size_t)G*128*4);
  float* cntf = (float*)alloc((size_t)G*4);
  char* zend = ws+off;
  int zwords = (int)((zend - zstart)/4);

  int nbScan  = (N+255)/256;     // 391 (<=512 for k_scan2)
  int gridN32 = (N+31)/32;
  int gridAgg = (N*64+255)/256;

  k_zero<<<(zwords+255)/256,256,0,stream>>>((float*)zstart, zwords);
  k_prep<<<1088,256,0,stream>>>(W_in, Wq, whh, HW, ggc, wih, CW, W1, W1cT);

  // CSR build
  k_hist<<<(E+255)/256,256,0,stream>>>(ei+E, deg, E);
  k_scan1<<<nbScan,256,0,stream>>>(deg, rowptr, bsum, N);
  k_scan2<<<1,512,0,stream>>>(bsum, nbScan, rowptr);
  k_scan3<<<nbScan,256,0,stream>>>(rowptr, bsum, N);
  k_fill<<<(E+255)/256,256,0,stream>>>(ei, deg, rowptr, col, E);

  // input GEMM + BN1
  k_gemm_in<<<gridN32,256,0,stream>>>(x, Wq, b_in, buf0, sumP1, sqP1, N);
  k_bn_fin<<<1,128,0,stream>>>(sumP1, sqP1, 64, 1.0f/(float)N, bn1_g, bn1_b, sc1, sh1);
  k_apply_bn1<<<(N*128/4+255)/256,256,0,stream>>>((const float4*)buf0, sc1, sh1, (float4*)h0, N*128/4);

  // 4 GRU steps: agg into s-buffer, gemm_gru writes h in-place over s
  k_agg<<<gridAgg,256,0,stream>>>(h0,   buf0, rowptr, col, N);
  k_gemm_gru<<<gridN32,256,0,stream>>>(buf0, h0,   buf0, CW+0*49152, HW, bih, bhh, N, nullptr, nullptr);
  k_agg<<<gridAgg,256,0,stream>>>(buf0, buf2, rowptr, col, N);
  k_gemm_gru<<<gridN32,256,0,stream>>>(buf2, buf0, buf2, CW+1*49152, HW, bih, bhh, N, nullptr, nullptr);
  k_agg<<<gridAgg,256,0,stream>>>(buf2, buf0, rowptr, col, N);
  k_gemm_gru<<<gridN32,256,0,stream>>>(buf0, buf2, buf0, CW+2*49152, HW, bih, bhh, N, nullptr, nullptr);
  k_agg<<<gridAgg,256,0,stream>>>(buf0, buf2, rowptr, col, N);
  k_gemm_gru<<<gridN32,256,0,stream>>>(buf2, buf0, buf2, CW+3*49152, HW, bih, bhh, N, sumP2, sqP2);

  // BN2 + skip + pool (+count), head
  k_bn_fin<<<1,128,0,stream>>>(sumP2, sqP2, 64, 1.0f/(float)N, bn2_g, bn2_b, sc2, sh2);
  k_bn2_pool<<<(N+255)/256,256,0,stream>>>(buf2, h0, batch, sc2, sh2, pool, cntf, N);
  k_head1<<<G,128,0,stream>>>(pool, cntf, W1cT, b1, t3, sum3, sq3);
  k_bn_fin<<<1,128,0,stream>>>(sum3, sq3, 1, 1.0f/(float)G, bn3_g, bn3_b, sc3, sh3);
  k_head2<<<G,128,0,stream>>>(t3, sc3, sh3, W2, b2, out);
}

// Round 4
// 2577.426 us; speedup vs baseline: 1.0415x; 1.0415x over previous
//
#include <hip/hip_runtime.h>
#include <math.h>

// GNN: GatedGraphConv(4 steps) + BN/ReLU + mean-pool + MLP head. fp32, decoupled.
// C_i = ggc_w[i] @ gru_wih^T precomputed, so per step:
//   s = gather_sum(h[src] -> dst)   (k_agg, CSR, latency-optimized)
//   GRU(s@C_i, h@Whh^T)             (k_gemm_gru, LDS tile, quad-k weights)
// k_gemm_gru: 16-node tile / 8 nodes per thread (48 acc VGPRs) so ~5 waves/SIMD
// hide the L2 weight-load latency. Writes hout in-place over its own s rows.

#define EPSV 1e-5f

__device__ __forceinline__ float fsig(float x){
  return 1.0f/(1.0f+__expf(-x));
}
__device__ __forceinline__ float ftanh(float x){
  float ax = fabsf(x);
  float e = __expf(-2.0f*ax);
  float r = (1.0f-e)/(1.0f+e);
  return copysignf(r, x);
}

__global__ void k_zero(float* __restrict__ p, int n){
  int i = blockIdx.x*256+threadIdx.x;
  if (i<n) p[i]=0.0f;
}

// ---- fused prep: WtIn quad, HW quad, CW quad (=ggc@wih^T), W1cT ----
// Quad layouts pair k in groups of 4 for float4 loads in the GEMM inner loops.
//   Wq  [(k>>2)*512  + j*4 + (k&3)] = Win[j*128+k]
//   HWq [(k>>2)*1536 + c*4 + (k&3)] = whh[c*128+k]          (c = gate*128+j)
//   CWq [s*49152 + (k>>2)*1536 + c*4 + (k&3)] = sum_m ggc[s][k][m]*wih[c][m]
__global__ void k_prep(const float* __restrict__ Win, float* __restrict__ Wq,
                       const float* __restrict__ whh, float* __restrict__ HWq,
                       const float* __restrict__ ggc, const float* __restrict__ wih,
                       float* __restrict__ CWq,
                       const float* __restrict__ W1, float* __restrict__ W1cT){
  int i = blockIdx.x*256+threadIdx.x;
  if (i < 16384){
    int k=i>>7, j=i&127;
    Wq[(k>>2)*512 + j*4 + (k&3)] = Win[j*128+k];
  } else if (i < 65536){
    int r=i-16384; int k=r/384, c=r%384;
    HWq[(k>>2)*1536 + c*4 + (k&3)] = whh[c*128+k];
  } else if (i < 262144){
    int r=i-65536; int s=r/49152; int r2=r%49152; int k=r2/384; int c=r2%384;
    const float* g = ggc + s*16384 + k*128;
    const float* w = wih + c*128;
    float acc=0.f;
    for (int m=0;m<128;m++) acc += g[m]*w[m];
    CWq[s*49152 + (k>>2)*1536 + c*4 + (k&3)] = acc;
  } else if (i < 278528){
    int r=i-262144; int j=r>>7, o=r&127;
    W1cT[j*128+o] = W1[o*256+j] + W1[o*256+128+j];
  }
}

// t = x @ W_in^T + b_in, fused BN1 column stat partials (64-way)
__global__ __launch_bounds__(256,2) void k_gemm_in(
    const float* __restrict__ x, const float* __restrict__ Wq, const float* __restrict__ bin,
    float* __restrict__ X, float* __restrict__ sumP, float* __restrict__ sqP, int N)
{
  __shared__ __align__(16) float xl[32][128];
  __shared__ float red[2][128];
  int t=threadIdx.x;
  int nbase = blockIdx.x*32;
  for (int it=0; it<4; ++it){
    int f4 = it*256+t;            // 1024 float4s = 32x128 floats
    int n = f4>>5; int k=(f4&31)*4;
    int gn=nbase+n;
    float4 v = make_float4(0.f,0.f,0.f,0.f);
    if (gn<N) v = *(const float4*)&x[(size_t)gn*128+k];
    *(float4*)&xl[n][k]=v;
  }
  __syncthreads();
  int j=t&127, half=t>>7, nb=half*16;
  float acc[16];
  #pragma unroll
  for (int q=0;q<16;q++) acc[q]=0.f;
  for (int k=0;k<128;k+=4){
    float4 w = *(const float4*)&Wq[(k>>2)*512 + j*4];
    #pragma unroll
    for (int q=0;q<16;q++){
      float4 xv = *(const float4*)&xl[nb+q][k];
      acc[q] += xv.x*w.x + xv.y*w.y + xv.z*w.z + xv.w*w.w;
    }
  }
  float bv = bin[j];
  float ts=0.f, tq=0.f;
  #pragma unroll
  for (int q=0;q<16;q++){
    int n=nbase+nb+q;
    if (n<N){
      float tv=acc[q]+bv;
      X[(size_t)n*128+j]=tv;
      ts+=tv; tq+=tv*tv;
    }
  }
  int p = (blockIdx.x&63)*128+j;
  red[half][j]=ts; __syncthreads();
  if (half==0) atomicAdd(&sumP[p], red[0][j]+red[1][j]);
  __syncthreads();
  red[half][j]=tq; __syncthreads();
  if (half==0) atomicAdd(&sqP[p], red[0][j]+red[1][j]);
}

// reduce partials -> BN scale/shift
__global__ void k_bn_fin(const float* __restrict__ sumP, const float* __restrict__ sqP, int P, float invcnt,
                         const float* __restrict__ g, const float* __restrict__ b,
                         float* __restrict__ sc, float* __restrict__ sh){
  int j = threadIdx.x;
  if (j>=128) return;
  float s=0.f,q=0.f;
  for (int p=0;p<P;p++){ s+=sumP[p*128+j]; q+=sqP[p*128+j]; }
  float mu = s*invcnt;
  float var = fmaxf(q*invcnt - mu*mu, 0.f);
  float scale = g[j]*rsqrtf(var+EPSV);
  sc[j]=scale; sh[j]=b[j]-mu*scale;
}

// h0 = relu(t*sc+sh)
__global__ void k_apply_bn1(const float4* __restrict__ X, const float* __restrict__ sc,
                            const float* __restrict__ sh, float4* __restrict__ h0, int total4){
  int i = blockIdx.x*256+threadIdx.x;
  if (i>=total4) return;
  float4 t = X[i];
  int j0 = (i*4)&127;
  float4 s = *(const float4*)&sc[j0];
  float4 b = *(const float4*)&sh[j0];
  float4 o;
  o.x = fmaxf(t.x*s.x+b.x, 0.f);
  o.y = fmaxf(t.y*s.y+b.y, 0.f);
  o.z = fmaxf(t.z*s.z+b.z, 0.f);
  o.w = fmaxf(t.w*s.w+b.w, 0.f);
  h0[i]=o;
}

// ---- CSR build (rows = dst, cols = src) ----
__global__ void k_hist(const int* __restrict__ dst, int* __restrict__ deg, int E){
  int e = blockIdx.x*256+threadIdx.x;
  if (e<E) atomicAdd(&deg[dst[e]], 1);
}
__global__ void k_scan1(const int* __restrict__ deg, int* __restrict__ rowptr, int* __restrict__ bsum, int N){
  __shared__ int tmp[256];
  int t=threadIdx.x; int n=blockIdx.x*256+t;
  int v = (n<N)?deg[n]:0;
  tmp[t]=v;
  __syncthreads();
  for (int o=1;o<256;o<<=1){
    int add = (t>=o)? tmp[t-o] : 0;
    __syncthreads();
    tmp[t]+=add;
    __syncthreads();
  }
  if (n<N) rowptr[n+1]=tmp[t];
  if (t==255) bsum[blockIdx.x]=tmp[255];
}
// parallel scan of block sums (nb <= 512) -> exclusive
__global__ void k_scan2(int* bsum, int nb, int* rowptr){
  __shared__ int tmp[512];
  int t=threadIdx.x;
  int v = (t<nb)? bsum[t] : 0;
  tmp[t]=v; __syncthreads();
  for (int o=1;o<512;o<<=1){
    int add = (t>=o)? tmp[t-o] : 0;
    __syncthreads();
    tmp[t]+=add;
    __syncthreads();
  }
  if (t<nb) bsum[t]=tmp[t]-v;
  if (t==0) rowptr[0]=0;
}
__global__ void k_scan3(int* rowptr, const int* __restrict__ bsum, int N){
  int n = blockIdx.x*256+threadIdx.x;
  if (n<N) rowptr[n+1] += bsum[blockIdx.x];
}
// fill via atomicSub on deg (consumes deg; no cur array)
__global__ void k_fill(const int* __restrict__ ei, int* __restrict__ deg,
                       const int* __restrict__ rowptr, int* __restrict__ col, int E){
  int e = blockIdx.x*256+threadIdx.x;
  if (e<E){
    int d = ei[E+e];
    int old = atomicSub(&deg[d],1);
    col[rowptr[d] + old - 1] = ei[e];
  }
}

// s[n] = sum_{e in row n} h[col[e]]  — one wave per node, 4 rows in flight
__global__ __launch_bounds__(256,8) void k_agg(
    const float* __restrict__ h, float* __restrict__ s,
    const int* __restrict__ rowptr, const int* __restrict__ col, int N)
{
  int wave = (blockIdx.x*256+threadIdx.x)>>6;
  int lane = threadIdx.x&63;
  if (wave>=N) return;
  int e = rowptr[wave], e1 = rowptr[wave+1];
  float2 a0=make_float2(0.f,0.f), a1=a0, a2=a0, a3=a0;
  for (; e+3<e1; e+=4){
    int c0=col[e],c1=col[e+1],c2=col[e+2],c3=col[e+3];
    float2 v0 = *(const float2*)&h[(size_t)c0*128+lane*2];
    float2 v1 = *(const float2*)&h[(size_t)c1*128+lane*2];
    float2 v2 = *(const float2*)&h[(size_t)c2*128+lane*2];
    float2 v3 = *(const float2*)&h[(size_t)c3*128+lane*2];
    a0.x+=v0.x; a0.y+=v0.y; a1.x+=v1.x; a1.y+=v1.y;
    a2.x+=v2.x; a2.y+=v2.y; a3.x+=v3.x; a3.y+=v3.y;
  }
  for (; e<e1; e++){
    int c0=col[e];
    float2 v0 = *(const float2*)&h[(size_t)c0*128+lane*2];
    a0.x+=v0.x; a0.y+=v0.y;
  }
  float2 r;
  r.x=(a0.x+a1.x)+(a2.x+a3.x);
  r.y=(a0.y+a1.y)+(a2.y+a3.y);
  *(float2*)&s[(size_t)wave*128+lane*2]=r;
}

// GEMM (gi = s@C, gh = h@Whh^T) + GRU update. 16-node tile staged in LDS,
// 8 nodes per thread (48 acc VGPRs -> ~5 waves/SIMD for latency hiding).
// hout may alias s (block writes only its own staged rows). Optional fused
// column stats for BN2 (last step).
__global__ __launch_bounds__(256,4) void k_gemm_gru(
    const float* s, const float* __restrict__ hin, float* hout,
    const float* __restrict__ CW, const float* __restrict__ HW,
    const float* __restrict__ bih, const float* __restrict__ bhh, int N,
    float* __restrict__ sumP, float* __restrict__ sqP)
{
  __shared__ __align__(16) float sh[16][2][128];   // 16 KB
  __shared__ float red[2][128];
  int t = threadIdx.x;
  int nbase = blockIdx.x*16;
  for (int it=0; it<4; ++it){
    int f4 = it*256 + t;              // 1024 float4s = 16*2*128 floats
    int flat = f4*4;
    int n = flat>>8; int rem = flat&255; int which = rem>>7; int k = rem&127;
    int gn = nbase+n;
    float4 v = make_float4(0.f,0.f,0.f,0.f);
    if (gn<N){
      const float* src = which ? &hin[(size_t)gn*128+k] : &s[(size_t)gn*128+k];
      v = *(const float4*)src;
    }
    *(float4*)&sh[n][which][k] = v;
  }
  __syncthreads();
  int j=t&127, half=t>>7, nb=half*8;
  float air[8],aiz[8],ain[8],ahr[8],ahz[8],ahn[8];
  #pragma unroll
  for (int q=0;q<8;q++){ air[q]=0.f;aiz[q]=0.f;ain[q]=0.f;ahr[q]=0.f;ahz[q]=0.f;ahn[q]=0.f; }
  for (int k=0;k<128;k+=4){
    const float* cwb = &CW[(k>>2)*1536];
    const float* hwb = &HW[(k>>2)*1536];
    float4 wir = *(const float4*)&cwb[j*4];
    float4 wiz = *(const float4*)&cwb[512 + j*4];
    float4 win = *(const float4*)&cwb[1024 + j*4];
    float4 whr = *(const float4*)&hwb[j*4];
    float4 whz = *(const float4*)&hwb[512 + j*4];
    float4 whn = *(const float4*)&hwb[1024 + j*4];
    #pragma unroll
    for (int q=0;q<8;q++){
      float4 sv = *(const float4*)&sh[nb+q][0][k];
      float4 hv = *(const float4*)&sh[nb+q][1][k];
      air[q] += sv.x*wir.x + sv.y*wir.y + sv.z*wir.z + sv.w*wir.w;
      aiz[q] += sv.x*wiz.x + sv.y*wiz.y + sv.z*wiz.z + sv.w*wiz.w;
      ain[q] += sv.x*win.x + sv.y*win.y + sv.z*win.z + sv.w*win.w;
      ahr[q] += hv.x*whr.x + hv.y*whr.y + hv.z*whr.z + hv.w*whr.w;
      ahz[q] += hv.x*whz.x + hv.y*whz.y + hv.z*whz.z + hv.w*whz.w;
      ahn[q] += hv.x*whn.x + hv.y*whn.y + hv.z*whn.z + hv.w*whn.w;
    }
  }
  float br=bih[j], bz=bih[128+j], bn_=bih[256+j];
  float cr=bhh[j], cz=bhh[128+j], cn=bhh[256+j];
  float ts=0.f, tq=0.f;
  #pragma unroll
  for (int q=0;q<8;q++){
    int n = nbase+nb+q;
    if (n<N){
      float r = fsig((air[q]+br) + (ahr[q]+cr));
      float z = fsig((aiz[q]+bz) + (ahz[q]+cz));
      float nn = ftanh((ain[q]+bn_) + r*(ahn[q]+cn));
      float hold = sh[nb+q][1][j];
      float hv2 = (1.f-z)*nn + z*hold;
      hout[(size_t)n*128+j]=hv2;
      ts+=hv2; tq+=hv2*hv2;
    }
  }
  if (sumP){
    red[half][j]=ts; __syncthreads();
    if (half==0) atomicAdd(&sumP[(blockIdx.x&63)*128+j], red[0][j]+red[1][j]);
    __syncthreads();
    red[half][j]=tq; __syncthreads();
    if (half==0) atomicAdd(&sqP[(blockIdx.x&63)*128+j], red[0][j]+red[1][j]);
  }
}

// hf = relu(bn2(h)+skip), run-length pooled (batch sorted) + fused node count
__global__ void k_bn2_pool(const float* __restrict__ hfin, const float* __restrict__ h0,
                           const int* __restrict__ batch, const float* __restrict__ sc,
                           const float* __restrict__ sh, float* __restrict__ pool,
                           float* __restrict__ cntf, int N){
  int t=threadIdx.x, j=t&127, half=t>>7;
  int n0 = blockIdx.x*256 + half*128;
  float scv=sc[j], shv=sh[j];
  int curg=-1; float acc=0.f, cacc=0.f;
  for (int r=0;r<128;r++){
    int n=n0+r; if (n>=N) break;
    int g = batch[n];
    float v = fmaxf(hfin[(size_t)n*128+j]*scv+shv + h0[(size_t)n*128+j], 0.f);
    if (g!=curg){
      if (curg>=0){
        atomicAdd(&pool[curg*128+j], acc);
        if (j==0) atomicAdd(&cntf[curg], cacc);
      }
      curg=g; acc=0.f; cacc=0.f;
    }
    acc+=v; cacc+=1.f;
  }
  if (curg>=0){
    atomicAdd(&pool[curg*128+j], acc);
    if (j==0) atomicAdd(&cntf[curg], cacc);
  }
}

// t3[g][o] = b1[o] + mean[g]·W1cT[:,o]; + BN3 stat atomics
__global__ void k_head1(const float* __restrict__ pool, const float* __restrict__ cntf,
                        const float* __restrict__ W1cT, const float* __restrict__ b1,
                        float* __restrict__ t3, float* __restrict__ sum3, float* __restrict__ sq3){
  __shared__ float mean[128];
  int g=blockIdx.x, o=threadIdx.x;
  float inv = 1.0f/fmaxf(cntf[g],1.0f);
  mean[o] = pool[g*128+o]*inv;
  __syncthreads();
  float acc=0.f;
  for (int jj=0;jj<128;jj++) acc += mean[jj]*W1cT[jj*128+o];
  float v = acc + b1[o];
  t3[g*128+o]=v;
  atomicAdd(&sum3[o], v);
  atomicAdd(&sq3[o], v*v);
}

// y1 = relu(bn3(t3)); out = y1 @ W2^T + b2
__global__ void k_head2(const float* __restrict__ t3, const float* __restrict__ sc,
                        const float* __restrict__ sh, const float* __restrict__ W2,
                        const float* __restrict__ b2, float* __restrict__ out){
  __shared__ float y[128];
  int g=blockIdx.x, o=threadIdx.x;
  float v = fmaxf(t3[g*128+o]*sc[o]+sh[o], 0.f);
  y[o]=v; __syncthreads();
  if (o<2){
    float acc=b2[o];
    for (int k=0;k<128;k++) acc += y[k]*W2[o*128+k];
    out[g*2+o]=acc;
  }
}

extern "C" void kernel_launch(void* const* d_in, const int* in_sizes, int n_in,
                              void* d_out, int out_size, void* d_ws, size_t ws_size,
                              hipStream_t stream){
  (void)n_in; (void)ws_size;
  const float* x    = (const float*)d_in[0];
  const int*   ei   = (const int*)d_in[1];
  const int*   batch= (const int*)d_in[2];
  const float* W_in = (const float*)d_in[3];
  const float* b_in = (const float*)d_in[4];
  const float* bn1_g= (const float*)d_in[5];
  const float* bn1_b= (const float*)d_in[6];
  const float* ggc  = (const float*)d_in[7];
  const float* wih  = (const float*)d_in[8];
  const float* whh  = (const float*)d_in[9];
  const float* bih  = (const float*)d_in[10];
  const float* bhh  = (const float*)d_in[11];
  const float* bn2_g= (const float*)d_in[12];
  const float* bn2_b= (const float*)d_in[13];
  const float* W1   = (const float*)d_in[14];
  const float* b1   = (const float*)d_in[15];
  const float* bn3_g= (const float*)d_in[16];
  const float* bn3_b= (const float*)d_in[17];
  const float* W2   = (const float*)d_in[18];
  const float* b2   = (const float*)d_in[19];
  float* out = (float*)d_out;

  int N = in_sizes[0]/128;
  int E = in_sizes[1]/2;
  int G = out_size/2;

  char* ws = (char*)d_ws;
  size_t off=0;
  auto alloc=[&](size_t bytes)->char*{
    char* p = ws+off; off = (off+bytes+255) & ~(size_t)255; return p;
  };
  float* buf0 = (float*)alloc((size_t)N*128*4);   // t -> s1/h1 -> s3/h3
  float* h0   = (float*)alloc((size_t)N*128*4);   // skip (persist)
  float* buf2 = (float*)alloc((size_t)N*128*4);   // s2/h2 -> s4/h4
  float* CW   = (float*)alloc((size_t)4*49152*4);
  float* HW   = (float*)alloc((size_t)49152*4);
  float* Wq   = (float*)alloc((size_t)16384*4);
  float* W1cT = (float*)alloc((size_t)16384*4);
  int* rowptr = (int*)alloc((size_t)(N+1)*4);
  int* col    = (int*)alloc((size_t)E*4);
  int* bsum   = (int*)alloc((size_t)512*4);
  float* t3   = (float*)alloc((size_t)G*128*4);
  float* sc1 = (float*)alloc(512); float* sh1 = (float*)alloc(512);
  float* sc2 = (float*)alloc(512); float* sh2 = (float*)alloc(512);
  float* sc3 = (float*)alloc(512); float* sh3 = (float*)alloc(512);
  // --- zero region (contiguous) ---
  char* zstart = ws+off;
  int*   deg  = (int*)alloc((size_t)N*4);
  float* sumP1= (float*)alloc((size_t)64*128*4);
  float* sqP1 = (float*)alloc((size_t)64*128*4);
  float* sumP2= (float*)alloc((size_t)64*128*4);
  float* sqP2 = (float*)alloc((size_t)64*128*4);
  float* sum3 = (float*)alloc(512);
  float* sq3  = (float*)alloc(512);
  float* pool = (float*)alloc((size_t)G*128*4);
  float* cntf = (float*)alloc((size_t)G*4);
  char* zend = ws+off;
  int zwords = (int)((zend - zstart)/4);

  int nbScan  = (N+255)/256;     // 391 (<=512 for k_scan2)
  int gridN32 = (N+31)/32;
  int gridN16 = (N+15)/16;
  int gridAgg = (N*64+255)/256;

  k_zero<<<(zwords+255)/256,256,0,stream>>>((float*)zstart, zwords);
  k_prep<<<1088,256,0,stream>>>(W_in, Wq, whh, HW, ggc, wih, CW, W1, W1cT);

  // CSR build
  k_hist<<<(E+255)/256,256,0,stream>>>(ei+E, deg, E);
  k_scan1<<<nbScan,256,0,stream>>>(deg, rowptr, bsum, N);
  k_scan2<<<1,512,0,stream>>>(bsum, nbScan, rowptr);
  k_scan3<<<nbScan,256,0,stream>>>(rowptr, bsum, N);
  k_fill<<<(E+255)/256,256,0,stream>>>(ei, deg, rowptr, col, E);

  // input GEMM + BN1
  k_gemm_in<<<gridN32,256,0,stream>>>(x, Wq, b_in, buf0, sumP1, sqP1, N);
  k_bn_fin<<<1,128,0,stream>>>(sumP1, sqP1, 64, 1.0f/(float)N, bn1_g, bn1_b, sc1, sh1);
  k_apply_bn1<<<(N*128/4+255)/256,256,0,stream>>>((const float4*)buf0, sc1, sh1, (float4*)h0, N*128/4);

  // 4 GRU steps: agg into s-buffer, gemm_gru writes h in-place over s
  k_agg<<<gridAgg,256,0,stream>>>(h0,   buf0, rowptr, col, N);
  k_gemm_gru<<<gridN16,256,0,stream>>>(buf0, h0,   buf0, CW+0*49152, HW, bih, bhh, N, nullptr, nullptr);
  k_agg<<<gridAgg,256,0,stream>>>(buf0, buf2, rowptr, col, N);
  k_gemm_gru<<<gridN16,256,0,stream>>>(buf2, buf0, buf2, CW+1*49152, HW, bih, bhh, N, nullptr, nullptr);
  k_agg<<<gridAgg,256,0,stream>>>(buf2, buf0, rowptr, col, N);
  k_gemm_gru<<<gridN16,256,0,stream>>>(buf0, buf2, buf0, CW+2*49152, HW, bih, bhh, N, nullptr, nullptr);
  k_agg<<<gridAgg,256,0,stream>>>(buf0, buf2, rowptr, col, N);
  k_gemm_gru<<<gridN16,256,0,stream>>>(buf2, buf0, buf2, CW+3*49152, HW, bih, bhh, N, sumP2, sqP2);

  // BN2 + skip + pool (+count), head
  k_bn_fin<<<1,128,0,stream>>>(sumP2, sqP2, 64, 1.0f/(float)N, bn2_g, bn2_b, sc2, sh2);
  k_bn2_pool<<<(N+255)/256,256,0,stream>>>(buf2, h0, batch, sc2, sh2, pool, cntf, N);
  k_head1<<<G,128,0,stream>>>(pool, cntf, W1cT, b1, t3, sum3, sq3);
  k_bn_fin<<<1,128,0,stream>>>(sum3, sq3, 1, 1.0f/(float)G, bn3_g, bn3_b, sc3, sh3);
  k_head2<<<G,128,0,stream>>>(t3, sc3, sh3, W2, b2, out);
}

// Round 7
// 2466.837 us; speedup vs baseline: 1.0882x; 1.0448x over previous
//
#include <hip/hip_runtime.h>
#include <math.h>

// GNN: GatedGraphConv(4 steps) + BN/ReLU + mean-pool + MLP head. fp32, decoupled.
// C_i = ggc_w[i] @ gru_wih^T precomputed, so per step:
//   s = gather_sum(h[src] -> dst)   (k_agg, CSR, latency-optimized)
//   GRU(s@C_i, h@Whh^T)             (k_gemm_gru, LDS tile, quad-k weights)
// k_gemm_gru: 16-node tile / 8 nodes per thread (48 acc VGPRs).
// launch_bounds(256,2): cap 128 VGPR -> ~90-100 used, NO SPILL (r4 at cap-64
// spilled: WRITE_SIZE +10.8MB, VGPR 64 < live set). Writes hout over own s rows.

#define EPSV 1e-5f

__device__ __forceinline__ float fsig(float x){
  return 1.0f/(1.0f+__expf(-x));
}
__device__ __forceinline__ float ftanh(float x){
  float ax = fabsf(x);
  float e = __expf(-2.0f*ax);
  float r = (1.0f-e)/(1.0f+e);
  return copysignf(r, x);
}

__global__ void k_zero(float* __restrict__ p, int n){
  int i = blockIdx.x*256+threadIdx.x;
  if (i<n) p[i]=0.0f;
}

// ---- fused prep: WtIn quad, HW quad, CW quad (=ggc@wih^T), W1cT ----
// Quad layouts pair k in groups of 4 for float4 loads in the GEMM inner loops.
//   Wq  [(k>>2)*512  + j*4 + (k&3)] = Win[j*128+k]
//   HWq [(k>>2)*1536 + c*4 + (k&3)] = whh[c*128+k]          (c = gate*128+j)
//   CWq [s*49152 + (k>>2)*1536 + c*4 + (k&3)] = sum_m ggc[s][k][m]*wih[c][m]
__global__ void k_prep(const float* __restrict__ Win, float* __restrict__ Wq,
                       const float* __restrict__ whh, float* __restrict__ HWq,
                       const float* __restrict__ ggc, const float* __restrict__ wih,
                       float* __restrict__ CWq,
                       const float* __restrict__ W1, float* __restrict__ W1cT){
  int i = blockIdx.x*256+threadIdx.x;
  if (i < 16384){
    int k=i>>7, j=i&127;
    Wq[(k>>2)*512 + j*4 + (k&3)] = Win[j*128+k];
  } else if (i < 65536){
    int r=i-16384; int k=r/384, c=r%384;
    HWq[(k>>2)*1536 + c*4 + (k&3)] = whh[c*128+k];
  } else if (i < 262144){
    int r=i-65536; int s=r/49152; int r2=r%49152; int k=r2/384; int c=r2%384;
    const float* g = ggc + s*16384 + k*128;
    const float* w = wih + c*128;
    float acc=0.f;
    for (int m=0;m<128;m++) acc += g[m]*w[m];
    CWq[s*49152 + (k>>2)*1536 + c*4 + (k&3)] = acc;
  } else if (i < 278528){
    int r=i-262144; int j=r>>7, o=r&127;
    W1cT[j*128+o] = W1[o*256+j] + W1[o*256+128+j];
  }
}

// t = x @ W_in^T + b_in, fused BN1 column stat partials (64-way)
__global__ __launch_bounds__(256,2) void k_gemm_in(
    const float* __restrict__ x, const float* __restrict__ Wq, const float* __restrict__ bin,
    float* __restrict__ X, float* __restrict__ sumP, float* __restrict__ sqP, int N)
{
  __shared__ __align__(16) float xl[32][128];
  __shared__ float red[2][128];
  int t=threadIdx.x;
  int nbase = blockIdx.x*32;
  for (int it=0; it<4; ++it){
    int f4 = it*256+t;            // 1024 float4s = 32x128 floats
    int n = f4>>5; int k=(f4&31)*4;
    int gn=nbase+n;
    float4 v = make_float4(0.f,0.f,0.f,0.f);
    if (gn<N) v = *(const float4*)&x[(size_t)gn*128+k];
    *(float4*)&xl[n][k]=v;
  }
  __syncthreads();
  int j=t&127, half=t>>7, nb=half*16;
  float acc[16];
  #pragma unroll
  for (int q=0;q<16;q++) acc[q]=0.f;
  for (int k=0;k<128;k+=4){
    float4 w = *(const float4*)&Wq[(k>>2)*512 + j*4];
    #pragma unroll
    for (int q=0;q<16;q++){
      float4 xv = *(const float4*)&xl[nb+q][k];
      acc[q] += xv.x*w.x + xv.y*w.y + xv.z*w.z + xv.w*w.w;
    }
  }
  float bv = bin[j];
  float ts=0.f, tq=0.f;
  #pragma unroll
  for (int q=0;q<16;q++){
    int n=nbase+nb+q;
    if (n<N){
      float tv=acc[q]+bv;
      X[(size_t)n*128+j]=tv;
      ts+=tv; tq+=tv*tv;
    }
  }
  int p = (blockIdx.x&63)*128+j;
  red[half][j]=ts; __syncthreads();
  if (half==0) atomicAdd(&sumP[p], red[0][j]+red[1][j]);
  __syncthreads();
  red[half][j]=tq; __syncthreads();
  if (half==0) atomicAdd(&sqP[p], red[0][j]+red[1][j]);
}

// reduce partials -> BN scale/shift
__global__ void k_bn_fin(const float* __restrict__ sumP, const float* __restrict__ sqP, int P, float invcnt,
                         const float* __restrict__ g, const float* __restrict__ b,
                         float* __restrict__ sc, float* __restrict__ sh){
  int j = threadIdx.x;
  if (j>=128) return;
  float s=0.f,q=0.f;
  for (int p=0;p<P;p++){ s+=sumP[p*128+j]; q+=sqP[p*128+j]; }
  float mu = s*invcnt;
  float var = fmaxf(q*invcnt - mu*mu, 0.f);
  float scale = g[j]*rsqrtf(var+EPSV);
  sc[j]=scale; sh[j]=b[j]-mu*scale;
}

// h0 = relu(t*sc+sh)
__global__ void k_apply_bn1(const float4* __restrict__ X, const float* __restrict__ sc,
                            const float* __restrict__ sh, float4* __restrict__ h0, int total4){
  int i = blockIdx.x*256+threadIdx.x;
  if (i>=total4) return;
  float4 t = X[i];
  int j0 = (i*4)&127;
  float4 s = *(const float4*)&sc[j0];
  float4 b = *(const float4*)&sh[j0];
  float4 o;
  o.x = fmaxf(t.x*s.x+b.x, 0.f);
  o.y = fmaxf(t.y*s.y+b.y, 0.f);
  o.z = fmaxf(t.z*s.z+b.z, 0.f);
  o.w = fmaxf(t.w*s.w+b.w, 0.f);
  h0[i]=o;
}

// ---- CSR build (rows = dst, cols = src) ----
__global__ void k_hist(const int* __restrict__ dst, int* __restrict__ deg, int E){
  int e = blockIdx.x*256+threadIdx.x;
  if (e<E) atomicAdd(&deg[dst[e]], 1);
}
__global__ void k_scan1(const int* __restrict__ deg, int* __restrict__ rowptr, int* __restrict__ bsum, int N){
  __shared__ int tmp[256];
  int t=threadIdx.x; int n=blockIdx.x*256+t;
  int v = (n<N)?deg[n]:0;
  tmp[t]=v;
  __syncthreads();
  for (int o=1;o<256;o<<=1){
    int add = (t>=o)? tmp[t-o] : 0;
    __syncthreads();
    tmp[t]+=add;
    __syncthreads();
  }
  if (n<N) rowptr[n+1]=tmp[t];
  if (t==255) bsum[blockIdx.x]=tmp[255];
}
// parallel scan of block sums (nb <= 512) -> exclusive
__global__ void k_scan2(int* bsum, int nb, int* rowptr){
  __shared__ int tmp[512];
  int t=threadIdx.x;
  int v = (t<nb)? bsum[t] : 0;
  tmp[t]=v; __syncthreads();
  for (int o=1;o<512;o<<=1){
    int add = (t>=o)? tmp[t-o] : 0;
    __syncthreads();
    tmp[t]+=add;
    __syncthreads();
  }
  if (t<nb) bsum[t]=tmp[t]-v;
  if (t==0) rowptr[0]=0;
}
__global__ void k_scan3(int* rowptr, const int* __restrict__ bsum, int N){
  int n = blockIdx.x*256+threadIdx.x;
  if (n<N) rowptr[n+1] += bsum[blockIdx.x];
}
// fill via atomicSub on deg (consumes deg; no cur array)
__global__ void k_fill(const int* __restrict__ ei, int* __restrict__ deg,
                       const int* __restrict__ rowptr, int* __restrict__ col, int E){
  int e = blockIdx.x*256+threadIdx.x;
  if (e<E){
    int d = ei[E+e];
    int old = atomicSub(&deg[d],1);
    col[rowptr[d] + old - 1] = ei[e];
  }
}

// s[n] = sum_{e in row n} h[col[e]]  — one wave per node, 4 rows in flight
__global__ __launch_bounds__(256,8) void k_agg(
    const float* __restrict__ h, float* __restrict__ s,
    const int* __restrict__ rowptr, const int* __restrict__ col, int N)
{
  int wave = (blockIdx.x*256+threadIdx.x)>>6;
  int lane = threadIdx.x&63;
  if (wave>=N) return;
  int e = rowptr[wave], e1 = rowptr[wave+1];
  float2 a0=make_float2(0.f,0.f), a1=a0, a2=a0, a3=a0;
  for (; e+3<e1; e+=4){
    int c0=col[e],c1=col[e+1],c2=col[e+2],c3=col[e+3];
    float2 v0 = *(const float2*)&h[(size_t)c0*128+lane*2];
    float2 v1 = *(const float2*)&h[(size_t)c1*128+lane*2];
    float2 v2 = *(const float2*)&h[(size_t)c2*128+lane*2];
    float2 v3 = *(const float2*)&h[(size_t)c3*128+lane*2];
    a0.x+=v0.x; a0.y+=v0.y; a1.x+=v1.x; a1.y+=v1.y;
    a2.x+=v2.x; a2.y+=v2.y; a3.x+=v3.x; a3.y+=v3.y;
  }
  for (; e<e1; e++){
    int c0=col[e];
    float2 v0 = *(const float2*)&h[(size_t)c0*128+lane*2];
    a0.x+=v0.x; a0.y+=v0.y;
  }
  float2 r;
  r.x=(a0.x+a1.x)+(a2.x+a3.x);
  r.y=(a0.y+a1.y)+(a2.y+a3.y);
  *(float2*)&s[(size_t)wave*128+lane*2]=r;
}

// GEMM (gi = s@C, gh = h@Whh^T) + GRU update. 16-node tile staged in LDS,
// 8 nodes per thread (48 acc VGPRs). launch_bounds(256,2): no spill, 4 waves/SIMD.
// hout may alias s (block writes only its own staged rows). Optional fused
// column stats for BN2 (last step).
__global__ __launch_bounds__(256,2) void k_gemm_gru(
    const float* s, const float* __restrict__ hin, float* hout,
    const float* __restrict__ CW, const float* __restrict__ HW,
    const float* __restrict__ bih, const float* __restrict__ bhh, int N,
    float* __restrict__ sumP, float* __restrict__ sqP)
{
  __shared__ __align__(16) float sh[16][2][128];   // 16 KB
  __shared__ float red[2][128];
  int t = threadIdx.x;
  int nbase = blockIdx.x*16;
  for (int it=0; it<4; ++it){
    int f4 = it*256 + t;              // 1024 float4s = 16*2*128 floats
    int flat = f4*4;
    int n = flat>>8; int rem = flat&255; int which = rem>>7; int k = rem&127;
    int gn = nbase+n;
    float4 v = make_float4(0.f,0.f,0.f,0.f);
    if (gn<N){
      const float* src = which ? &hin[(size_t)gn*128+k] : &s[(size_t)gn*128+k];
      v = *(const float4*)src;
    }
    *(float4*)&sh[n][which][k] = v;
  }
  __syncthreads();
  int j=t&127, half=t>>7, nb=half*8;
  float air[8],aiz[8],ain[8],ahr[8],ahz[8],ahn[8];
  #pragma unroll
  for (int q=0;q<8;q++){ air[q]=0.f;aiz[q]=0.f;ain[q]=0.f;ahr[q]=0.f;ahz[q]=0.f;ahn[q]=0.f; }
  for (int k=0;k<128;k+=4){
    const float* cwb = &CW[(k>>2)*1536];
    const float* hwb = &HW[(k>>2)*1536];
    float4 wir = *(const float4*)&cwb[j*4];
    float4 wiz = *(const float4*)&cwb[512 + j*4];
    float4 win = *(const float4*)&cwb[1024 + j*4];
    float4 whr = *(const float4*)&hwb[j*4];
    float4 whz = *(const float4*)&hwb[512 + j*4];
    float4 whn = *(const float4*)&hwb[1024 + j*4];
    #pragma unroll
    for (int q=0;q<8;q++){
      float4 sv = *(const float4*)&sh[nb+q][0][k];
      float4 hv = *(const float4*)&sh[nb+q][1][k];
      air[q] += sv.x*wir.x + sv.y*wir.y + sv.z*wir.z + sv.w*wir.w;
      aiz[q] += sv.x*wiz.x + sv.y*wiz.y + sv.z*wiz.z + sv.w*wiz.w;
      ain[q] += sv.x*win.x + sv.y*win.y + sv.z*win.z + sv.w*win.w;
      ahr[q] += hv.x*whr.x + hv.y*whr.y + hv.z*whr.z + hv.w*whr.w;
      ahz[q] += hv.x*whz.x + hv.y*whz.y + hv.z*whz.z + hv.w*whz.w;
      ahn[q] += hv.x*whn.x + hv.y*whn.y + hv.z*whn.z + hv.w*whn.w;
    }
  }
  float br=bih[j], bz=bih[128+j], bn_=bih[256+j];
  float cr=bhh[j], cz=bhh[128+j], cn=bhh[256+j];
  float ts=0.f, tq=0.f;
  #pragma unroll
  for (int q=0;q<8;q++){
    int n = nbase+nb+q;
    if (n<N){
      float r = fsig((air[q]+br) + (ahr[q]+cr));
      float z = fsig((aiz[q]+bz) + (ahz[q]+cz));
      float nn = ftanh((ain[q]+bn_) + r*(ahn[q]+cn));
      float hold = sh[nb+q][1][j];
      float hv2 = (1.f-z)*nn + z*hold;
      hout[(size_t)n*128+j]=hv2;
      ts+=hv2; tq+=hv2*hv2;
    }
  }
  if (sumP){
    red[half][j]=ts; __syncthreads();
    if (half==0) atomicAdd(&sumP[(blockIdx.x&63)*128+j], red[0][j]+red[1][j]);
    __syncthreads();
    red[half][j]=tq; __syncthreads();
    if (half==0) atomicAdd(&sqP[(blockIdx.x&63)*128+j], red[0][j]+red[1][j]);
  }
}

// hf = relu(bn2(h)+skip), run-length pooled (batch sorted) + fused node count
__global__ void k_bn2_pool(const float* __restrict__ hfin, const float* __restrict__ h0,
                           const int* __restrict__ batch, const float* __restrict__ sc,
                           const float* __restrict__ sh, float* __restrict__ pool,
                           float* __restrict__ cntf, int N){
  int t=threadIdx.x, j=t&127, half=t>>7;
  int n0 = blockIdx.x*256 + half*128;
  float scv=sc[j], shv=sh[j];
  int curg=-1; float acc=0.f, cacc=0.f;
  for (int r=0;r<128;r++){
    int n=n0+r; if (n>=N) break;
    int g = batch[n];
    float v = fmaxf(hfin[(size_t)n*128+j]*scv+shv + h0[(size_t)n*128+j], 0.f);
    if (g!=curg){
      if (curg>=0){
        atomicAdd(&pool[curg*128+j], acc);
        if (j==0) atomicAdd(&cntf[curg], cacc);
      }
      curg=g; acc=0.f; cacc=0.f;
    }
    acc+=v; cacc+=1.f;
  }
  if (curg>=0){
    atomicAdd(&pool[curg*128+j], acc);
    if (j==0) atomicAdd(&cntf[curg], cacc);
  }
}

// t3[g][o] = b1[o] + mean[g]·W1cT[:,o]; + BN3 stat atomics
__global__ void k_head1(const float* __restrict__ pool, const float* __restrict__ cntf,
                        const float* __restrict__ W1cT, const float* __restrict__ b1,
                        float* __restrict__ t3, float* __restrict__ sum3, float* __restrict__ sq3){
  __shared__ float mean[128];
  int g=blockIdx.x, o=threadIdx.x;
  float inv = 1.0f/fmaxf(cntf[g],1.0f);
  mean[o] = pool[g*128+o]*inv;
  __syncthreads();
  float acc=0.f;
  for (int jj=0;jj<128;jj++) acc += mean[jj]*W1cT[jj*128+o];
  float v = acc + b1[o];
  t3[g*128+o]=v;
  atomicAdd(&sum3[o], v);
  atomicAdd(&sq3[o], v*v);
}

// y1 = relu(bn3(t3)); out = y1 @ W2^T + b2
__global__ void k_head2(const float* __restrict__ t3, const float* __restrict__ sc,
                        const float* __restrict__ sh, const float* __restrict__ W2,
                        const float* __restrict__ b2, float* __restrict__ out){
  __shared__ float y[128];
  int g=blockIdx.x, o=threadIdx.x;
  float v = fmaxf(t3[g*128+o]*sc[o]+sh[o], 0.f);
  y[o]=v; __syncthreads();
  if (o<2){
    float acc=b2[o];
    for (int k=0;k<128;k++) acc += y[k]*W2[o*128+k];
    out[g*2+o]=acc;
  }
}

extern "C" void kernel_launch(void* const* d_in, const int* in_sizes, int n_in,
                              void* d_out, int out_size, void* d_ws, size_t ws_size,
                              hipStream_t stream){
  (void)n_in; (void)ws_size;
  const float* x    = (const float*)d_in[0];
  const int*   ei   = (const int*)d_in[1];
  const int*   batch= (const int*)d_in[2];
  const float* W_in = (const float*)d_in[3];
  const float* b_in = (const float*)d_in[4];
  const float* bn1_g= (const float*)d_in[5];
  const float* bn1_b= (const float*)d_in[6];
  const float* ggc  = (const float*)d_in[7];
  const float* wih  = (const float*)d_in[8];
  const float* whh  = (const float*)d_in[9];
  const float* bih  = (const float*)d_in[10];
  const float* bhh  = (const float*)d_in[11];
  const float* bn2_g= (const float*)d_in[12];
  const float* bn2_b= (const float*)d_in[13];
  const float* W1   = (const float*)d_in[14];
  const float* b1   = (const float*)d_in[15];
  const float* bn3_g= (const float*)d_in[16];
  const float* bn3_b= (const float*)d_in[17];
  const float* W2   = (const float*)d_in[18];
  const float* b2   = (const float*)d_in[19];
  float* out = (float*)d_out;

  int N = in_sizes[0]/128;
  int E = in_sizes[1]/2;
  int G = out_size/2;

  char* ws = (char*)d_ws;
  size_t off=0;
  auto alloc=[&](size_t bytes)->char*{
    char* p = ws+off; off = (off+bytes+255) & ~(size_t)255; return p;
  };
  float* buf0 = (float*)alloc((size_t)N*128*4);   // t -> s1/h1 -> s3/h3
  float* h0   = (float*)alloc((size_t)N*128*4);   // skip (persist)
  float* buf2 = (float*)alloc((size_t)N*128*4);   // s2/h2 -> s4/h4
  float* CW   = (float*)alloc((size_t)4*49152*4);
  float* HW   = (float*)alloc((size_t)49152*4);
  float* Wq   = (float*)alloc((size_t)16384*4);
  float* W1cT = (float*)alloc((size_t)16384*4);
  int* rowptr = (int*)alloc((size_t)(N+1)*4);
  int* col    = (int*)alloc((size_t)E*4);
  int* bsum   = (int*)alloc((size_t)512*4);
  float* t3   = (float*)alloc((size_t)G*128*4);
  float* sc1 = (float*)alloc(512); float* sh1 = (float*)alloc(512);
  float* sc2 = (float*)alloc(512); float* sh2 = (float*)alloc(512);
  float* sc3 = (float*)alloc(512); float* sh3 = (float*)alloc(512);
  // --- zero region (contiguous) ---
  char* zstart = ws+off;
  int*   deg  = (int*)alloc((size_t)N*4);
  float* sumP1= (float*)alloc((size_t)64*128*4);
  float* sqP1 = (float*)alloc((size_t)64*128*4);
  float* sumP2= (float*)alloc((size_t)64*128*4);
  float* sqP2 = (float*)alloc((size_t)64*128*4);
  float* sum3 = (float*)alloc(512);
  float* sq3  = (float*)alloc(512);
  float* pool = (float*)alloc((size_t)G*128*4);
  float* cntf = (float*)alloc((size_t)G*4);
  char* zend = ws+off;
  int zwords = (int)((zend - zstart)/4);

  int nbScan  = (N+255)/256;     // 391 (<=512 for k_scan2)
  int gridN32 = (N+31)/32;
  int gridN16 = (N+15)/16;
  int gridAgg = (N*64+255)/256;

  k_zero<<<(zwords+255)/256,256,0,stream>>>((float*)zstart, zwords);
  k_prep<<<1088,256,0,stream>>>(W_in, Wq, whh, HW, ggc, wih, CW, W1, W1cT);

  // CSR build
  k_hist<<<(E+255)/256,256,0,stream>>>(ei+E, deg, E);
  k_scan1<<<nbScan,256,0,stream>>>(deg, rowptr, bsum, N);
  k_scan2<<<1,512,0,stream>>>(bsum, nbScan, rowptr);
  k_scan3<<<nbScan,256,0,stream>>>(rowptr, bsum, N);
  k_fill<<<(E+255)/256,256,0,stream>>>(ei, deg, rowptr, col, E);

  // input GEMM + BN1
  k_gemm_in<<<gridN32,256,0,stream>>>(x, Wq, b_in, buf0, sumP1, sqP1, N);
  k_bn_fin<<<1,128,0,stream>>>(sumP1, sqP1, 64, 1.0f/(float)N, bn1_g, bn1_b, sc1, sh1);
  k_apply_bn1<<<(N*128/4+255)/256,256,0,stream>>>((const float4*)buf0, sc1, sh1, (float4*)h0, N*128/4);

  // 4 GRU steps: agg into s-buffer, gemm_gru writes h in-place over s
  k_agg<<<gridAgg,256,0,stream>>>(h0,   buf0, rowptr, col, N);
  k_gemm_gru<<<gridN16,256,0,stream>>>(buf0, h0,   buf0, CW+0*49152, HW, bih, bhh, N, nullptr, nullptr);
  k_agg<<<gridAgg,256,0,stream>>>(buf0, buf2, rowptr, col, N);
  k_gemm_gru<<<gridN16,256,0,stream>>>(buf2, buf0, buf2, CW+1*49152, HW, bih, bhh, N, nullptr, nullptr);
  k_agg<<<gridAgg,256,0,stream>>>(buf2, buf0, rowptr, col, N);
  k_gemm_gru<<<gridN16,256,0,stream>>>(buf0, buf2, buf0, CW+2*49152, HW, bih, bhh, N, nullptr, nullptr);
  k_agg<<<gridAgg,256,0,stream>>>(buf0, buf2, rowptr, col, N);
  k_gemm_gru<<<gridN16,256,0,stream>>>(buf2, buf0, buf2, CW+3*49152, HW, bih, bhh, N, sumP2, sqP2);

  // BN2 + skip + pool (+count), head
  k_bn_fin<<<1,128,0,stream>>>(sumP2, sqP2, 64, 1.0f/(float)N, bn2_g, bn2_b, sc2, sh2);
  k_bn2_pool<<<(N+255)/256,256,0,stream>>>(buf2, h0, batch, sc2, sh2, pool, cntf, N);
  k_head1<<<G,128,0,stream>>>(pool, cntf, W1cT, b1, t3, sum3, sq3);
  k_bn_fin<<<1,128,0,stream>>>(sum3, sq3, 1, 1.0f/(float)G, bn3_g, bn3_b, sc3, sh3);
  k_head2<<<G,128,0,stream>>>(t3, sc3, sh3, W2, b2, out);
}

// Round 8
// 1494.138 us; speedup vs baseline: 1.7966x; 1.6510x over previous
//
#include <hip/hip_runtime.h>
#include <math.h>

// GNN: GatedGraphConv(4 steps) + BN/ReLU + mean-pool + MLP head.
// r8: GRU GEMM moved to split-bf16 MFMA (x = hi+lo bf16; 3 MFMAs per product,
// fp32-grade accuracy at ~790 TF effective vs 157 TF fp32 vector ceiling,
// which r3/r4/r7 showed is unreachable anyway: 2.6x VALU overhead, 27% eff).
// Combined GEMM: A=[s|h] (Nx256) @ B (256x512), col groups:
//   G0 = i_r+h_r, G1 = i_z+h_z, G2 = i_n, G3 = h_n  (zero blocks where unused)
// Block = 32 nodes, 4 waves; wave owns 32 j-cols across all 4 gates -> GRU
// epilogue is wave-local. A in LDS (XOR-swizzled bf16 hi/lo), B from L2.

#define EPSV 1e-5f

typedef __attribute__((ext_vector_type(8))) short bf16x8;
typedef __attribute__((ext_vector_type(4))) float f32x4;

__device__ __forceinline__ float fsig(float x){
  return 1.0f/(1.0f+__expf(-x));
}
__device__ __forceinline__ float ftanh(float x){
  float ax = fabsf(x);
  float e = __expf(-2.0f*ax);
  float r = (1.0f-e)/(1.0f+e);
  return copysignf(r, x);
}
__device__ __forceinline__ unsigned short bf16rne(float x){
  unsigned u = __float_as_uint(x);
  unsigned r = (u + 0x7FFFu + ((u>>16)&1u)) >> 16;
  return (unsigned short)r;
}
__device__ __forceinline__ float bf16tof(unsigned short h){
  return __uint_as_float(((unsigned)h)<<16);
}

__global__ void k_zero(float* __restrict__ p, int n){
  int i = blockIdx.x*256+threadIdx.x;
  if (i<n) p[i]=0.0f;
}

// Wq (input GEMM quad layout) + W1cT (head). grid 128.
__global__ void k_prep(const float* __restrict__ Win, float* __restrict__ Wq,
                       const float* __restrict__ W1, float* __restrict__ W1cT){
  int i = blockIdx.x*256+threadIdx.x;
  if (i < 16384){
    int k=i>>7, j=i&127;
    Wq[(k>>2)*512 + j*4 + (k&3)] = Win[j*128+k];
  } else if (i < 32768){
    int r=i-16384; int j=r>>7, o=r&127;
    W1cT[j*128+o] = W1[o*256+j] + W1[o*256+128+j];
  }
}

// Build B (4 steps x 256k x 512c) as bf16 hi/lo in MFMA fragment order:
//   off = st*131072 + ((k>>5)*512 + c)*32 + (k&31)   [shorts]
// k<128 (s-part): gr<3 -> CW[k][gr,j] = sum_m ggc[st][k][m]*wih[gr*128+j][m]; gr==3 -> 0
// k>=128 (h-part): gr!=2 -> whh[gate*128+j][k-128] (gate: 0,1,-,2); gr==2 -> 0
__global__ void k_prepB(const float* __restrict__ ggc, const float* __restrict__ wih,
                        const float* __restrict__ whh,
                        short* __restrict__ Bhi, short* __restrict__ Blo){
  int i = blockIdx.x*256+threadIdx.x;      // [0, 524288)
  int st = i>>17;
  int r  = i&131071;
  int k  = r>>9;
  int c  = r&511;
  int gr = c>>7, j = c&127;
  float val = 0.f;
  if (k<128){
    if (gr<3){
      const float* g = ggc + st*16384 + k*128;
      const float* w = wih + (gr*128+j)*128;
      float acc=0.f;
      for (int m=0;m<128;m++) acc += g[m]*w[m];
      val = acc;
    }
  } else {
    int kh = k-128;
    if (gr!=2){
      int gate = (gr==3)?2:gr;
      val = whh[(gate*128+j)*128 + kh];
    }
  }
  unsigned short h = bf16rne(val);
  unsigned short lo = bf16rne(val - bf16tof(h));
  size_t off = (size_t)st*131072 + ((size_t)(k>>5)*512 + (size_t)c)*32 + (size_t)(k&31);
  Bhi[off]=(short)h; Blo[off]=(short)lo;
}

// t = x @ W_in^T + b_in, fused BN1 column stat partials (64-way)
__global__ __launch_bounds__(256,2) void k_gemm_in(
    const float* __restrict__ x, const float* __restrict__ Wq, const float* __restrict__ bin,
    float* __restrict__ X, float* __restrict__ sumP, float* __restrict__ sqP, int N)
{
  __shared__ __align__(16) float xl[32][128];
  __shared__ float red[2][128];
  int t=threadIdx.x;
  int nbase = blockIdx.x*32;
  for (int it=0; it<4; ++it){
    int f4 = it*256+t;
    int n = f4>>5; int k=(f4&31)*4;
    int gn=nbase+n;
    float4 v = make_float4(0.f,0.f,0.f,0.f);
    if (gn<N) v = *(const float4*)&x[(size_t)gn*128+k];
    *(float4*)&xl[n][k]=v;
  }
  __syncthreads();
  int j=t&127, half=t>>7, nb=half*16;
  float acc[16];
  #pragma unroll
  for (int q=0;q<16;q++) acc[q]=0.f;
  for (int k=0;k<128;k+=4){
    float4 w = *(const float4*)&Wq[(k>>2)*512 + j*4];
    #pragma unroll
    for (int q=0;q<16;q++){
      float4 xv = *(const float4*)&xl[nb+q][k];
      acc[q] += xv.x*w.x + xv.y*w.y + xv.z*w.z + xv.w*w.w;
    }
  }
  float bv = bin[j];
  float ts=0.f, tq=0.f;
  #pragma unroll
  for (int q=0;q<16;q++){
    int n=nbase+nb+q;
    if (n<N){
      float tv=acc[q]+bv;
      X[(size_t)n*128+j]=tv;
      ts+=tv; tq+=tv*tv;
    }
  }
  int p = (blockIdx.x&63)*128+j;
  red[half][j]=ts; __syncthreads();
  if (half==0) atomicAdd(&sumP[p], red[0][j]+red[1][j]);
  __syncthreads();
  red[half][j]=tq; __syncthreads();
  if (half==0) atomicAdd(&sqP[p], red[0][j]+red[1][j]);
}

__global__ void k_bn_fin(const float* __restrict__ sumP, const float* __restrict__ sqP, int P, float invcnt,
                         const float* __restrict__ g, const float* __restrict__ b,
                         float* __restrict__ sc, float* __restrict__ sh){
  int j = threadIdx.x;
  if (j>=128) return;
  float s=0.f,q=0.f;
  for (int p=0;p<P;p++){ s+=sumP[p*128+j]; q+=sqP[p*128+j]; }
  float mu = s*invcnt;
  float var = fmaxf(q*invcnt - mu*mu, 0.f);
  float scale = g[j]*rsqrtf(var+EPSV);
  sc[j]=scale; sh[j]=b[j]-mu*scale;
}

__global__ void k_apply_bn1(const float4* __restrict__ X, const float* __restrict__ sc,
                            const float* __restrict__ sh, float4* __restrict__ h0, int total4){
  int i = blockIdx.x*256+threadIdx.x;
  if (i>=total4) return;
  float4 t = X[i];
  int j0 = (i*4)&127;
  float4 s = *(const float4*)&sc[j0];
  float4 b = *(const float4*)&sh[j0];
  float4 o;
  o.x = fmaxf(t.x*s.x+b.x, 0.f);
  o.y = fmaxf(t.y*s.y+b.y, 0.f);
  o.z = fmaxf(t.z*s.z+b.z, 0.f);
  o.w = fmaxf(t.w*s.w+b.w, 0.f);
  h0[i]=o;
}

// ---- CSR build (rows = dst, cols = src) ----
__global__ void k_hist(const int* __restrict__ dst, int* __restrict__ deg, int E){
  int e = blockIdx.x*256+threadIdx.x;
  if (e<E) atomicAdd(&deg[dst[e]], 1);
}
__global__ void k_scan1(const int* __restrict__ deg, int* __restrict__ rowptr, int* __restrict__ bsum, int N){
  __shared__ int tmp[256];
  int t=threadIdx.x; int n=blockIdx.x*256+t;
  int v = (n<N)?deg[n]:0;
  tmp[t]=v;
  __syncthreads();
  for (int o=1;o<256;o<<=1){
    int add = (t>=o)? tmp[t-o] : 0;
    __syncthreads();
    tmp[t]+=add;
    __syncthreads();
  }
  if (n<N) rowptr[n+1]=tmp[t];
  if (t==255) bsum[blockIdx.x]=tmp[255];
}
__global__ void k_scan2(int* bsum, int nb, int* rowptr){
  __shared__ int tmp[512];
  int t=threadIdx.x;
  int v = (t<nb)? bsum[t] : 0;
  tmp[t]=v; __syncthreads();
  for (int o=1;o<512;o<<=1){
    int add = (t>=o)? tmp[t-o] : 0;
    __syncthreads();
    tmp[t]+=add;
    __syncthreads();
  }
  if (t<nb) bsum[t]=tmp[t]-v;
  if (t==0) rowptr[0]=0;
}
__global__ void k_scan3(int* rowptr, const int* __restrict__ bsum, int N){
  int n = blockIdx.x*256+threadIdx.x;
  if (n<N) rowptr[n+1] += bsum[blockIdx.x];
}
__global__ void k_fill(const int* __restrict__ ei, int* __restrict__ deg,
                       const int* __restrict__ rowptr, int* __restrict__ col, int E){
  int e = blockIdx.x*256+threadIdx.x;
  if (e<E){
    int d = ei[E+e];
    int old = atomicSub(&deg[d],1);
    col[rowptr[d] + old - 1] = ei[e];
  }
}

// s[n] = sum_{e in row n} h[col[e]]  — one wave per node, 4 rows in flight
__global__ __launch_bounds__(256,8) void k_agg(
    const float* __restrict__ h, float* __restrict__ s,
    const int* __restrict__ rowptr, const int* __restrict__ col, int N)
{
  int wave = (blockIdx.x*256+threadIdx.x)>>6;
  int lane = threadIdx.x&63;
  if (wave>=N) return;
  int e = rowptr[wave], e1 = rowptr[wave+1];
  float2 a0=make_float2(0.f,0.f), a1=a0, a2=a0, a3=a0;
  for (; e+3<e1; e+=4){
    int c0=col[e],c1=col[e+1],c2=col[e+2],c3=col[e+3];
    float2 v0 = *(const float2*)&h[(size_t)c0*128+lane*2];
    float2 v1 = *(const float2*)&h[(size_t)c1*128+lane*2];
    float2 v2 = *(const float2*)&h[(size_t)c2*128+lane*2];
    float2 v3 = *(const float2*)&h[(size_t)c3*128+lane*2];
    a0.x+=v0.x; a0.y+=v0.y; a1.x+=v1.x; a1.y+=v1.y;
    a2.x+=v2.x; a2.y+=v2.y; a3.x+=v3.x; a3.y+=v3.y;
  }
  for (; e<e1; e++){
    int c0=col[e];
    float2 v0 = *(const float2*)&h[(size_t)c0*128+lane*2];
    a0.x+=v0.x; a0.y+=v0.y;
  }
  float2 r;
  r.x=(a0.x+a1.x)+(a2.x+a3.x);
  r.y=(a0.y+a1.y)+(a2.y+a3.y);
  *(float2*)&s[(size_t)wave*128+lane*2]=r;
}

// Split-bf16 MFMA GRU. Block = 32 nodes, 4 waves.
// A = [s|h] rows staged to LDS as bf16 hi/lo, XOR-swizzled 16B granules.
// Wave wv owns j in [wv*32, wv*32+32): 2 M-tiles x 8 N-tiles (4 gates x 2 jt).
// mfma_f32_16x16x32_bf16: A lane: row=l&15, k=(l>>4)*8+[0..7];
//                         B lane: col=l&15, k=(l>>4)*8+[0..7];
//                         D lane: col=l&15, row=(l>>4)*4+reg.
__global__ __launch_bounds__(256,2) void k_gru_mfma(
    const float* __restrict__ s, const float* __restrict__ hin, float* __restrict__ hout,
    const short* __restrict__ Bhi, const short* __restrict__ Blo,
    const float* __restrict__ bih, const float* __restrict__ bhh, int N,
    float* __restrict__ sumP, float* __restrict__ sqP)
{
  __shared__ short Ahi[32*256];   // 16 KB
  __shared__ short Alo[32*256];   // 16 KB
  int t = threadIdx.x;
  int nbase = blockIdx.x*32;

  // ---- stage A: 32 rows x 256 k (k<128 from s, k>=128 from h), hi/lo split ----
  for (int it=0; it<8; ++it){
    int f4 = it*256 + t;            // [0,2048) float4 chunks
    int row = f4>>6;                // 64 float4 per row
    int c4  = f4&63;                // k = c4*4
    int k   = c4*4;
    int n   = nbase + row;
    float4 v = make_float4(0.f,0.f,0.f,0.f);
    if (n < N){
      const float* src = (k<128) ? &s[(size_t)n*128 + k] : &hin[(size_t)n*128 + (k-128)];
      v = *(const float4*)src;
    }
    unsigned short h0=bf16rne(v.x), h1=bf16rne(v.y), h2=bf16rne(v.z), h3=bf16rne(v.w);
    unsigned short l0=bf16rne(v.x-bf16tof(h0)), l1=bf16rne(v.y-bf16tof(h1));
    unsigned short l2=bf16rne(v.z-bf16tof(h2)), l3=bf16rne(v.w-bf16tof(h3));
    int g = c4>>1, half = c4&1;
    int gs = g ^ (row&7);
    int off = row*256 + gs*8 + half*4;     // shorts
    uint2 H; H.x = (unsigned)h0 | ((unsigned)h1<<16); H.y = (unsigned)h2 | ((unsigned)h3<<16);
    uint2 L; L.x = (unsigned)l0 | ((unsigned)l1<<16); L.y = (unsigned)l2 | ((unsigned)l3<<16);
    *(uint2*)&Ahi[off] = H;
    *(uint2*)&Alo[off] = L;
  }
  __syncthreads();

  int wv = t>>6, l = t&63;
  int lj = l&15, lk = l>>4;

  f32x4 acc[2][8];
  #pragma unroll
  for (int mt=0; mt<2; ++mt)
    #pragma unroll
    for (int nt=0; nt<8; ++nt)
      acc[mt][nt] = (f32x4){0.f,0.f,0.f,0.f};

  for (int kc=0; kc<8; ++kc){
    bf16x8 a_hi[2], a_lo[2];
    #pragma unroll
    for (int mt=0; mt<2; ++mt){
      int r = mt*16 + lj;
      int g = kc*4 + lk;
      int off = r*256 + ((g ^ (r&7))<<3);
      a_hi[mt] = *(bf16x8*)&Ahi[off];
      a_lo[mt] = *(bf16x8*)&Alo[off];
    }
    #pragma unroll
    for (int gr=0; gr<4; ++gr){
      #pragma unroll
      for (int jt=0; jt<2; ++jt){
        int nt = gr*2 + jt;
        int c  = gr*128 + wv*32 + jt*16 + lj;
        size_t boff = ((size_t)kc*512 + (size_t)c)*32 + (size_t)lk*8;
        bf16x8 b_hi = *(const bf16x8*)&Bhi[boff];
        bf16x8 b_lo = *(const bf16x8*)&Blo[boff];
        acc[0][nt] = __builtin_amdgcn_mfma_f32_16x16x32_bf16(a_hi[0], b_hi, acc[0][nt], 0,0,0);
        acc[1][nt] = __builtin_amdgcn_mfma_f32_16x16x32_bf16(a_hi[1], b_hi, acc[1][nt], 0,0,0);
        acc[0][nt] = __builtin_amdgcn_mfma_f32_16x16x32_bf16(a_lo[0], b_hi, acc[0][nt], 0,0,0);
        acc[1][nt] = __builtin_amdgcn_mfma_f32_16x16x32_bf16(a_lo[1], b_hi, acc[1][nt], 0,0,0);
        acc[0][nt] = __builtin_amdgcn_mfma_f32_16x16x32_bf16(a_hi[0], b_lo, acc[0][nt], 0,0,0);
        acc[1][nt] = __builtin_amdgcn_mfma_f32_16x16x32_bf16(a_hi[1], b_lo, acc[1][nt], 0,0,0);
      }
    }
  }

  // ---- GRU epilogue (wave-local): G0=r, G1=z, G2=i_n, G3=h_n ----
  #pragma unroll
  for (int jt=0; jt<2; ++jt){
    int j = wv*32 + jt*16 + lj;
    float br=bih[j], bz=bih[128+j], bn_=bih[256+j];
    float cr=bhh[j], cz=bhh[128+j], cn=bhh[256+j];
    float ts=0.f, tq=0.f;
    #pragma unroll
    for (int mt=0; mt<2; ++mt){
      #pragma unroll
      for (int rg=0; rg<4; ++rg){
        int n = nbase + mt*16 + lk*4 + rg;
        if (n < N){
          float r  = fsig(acc[mt][0+jt][rg] + br + cr);
          float z  = fsig(acc[mt][2+jt][rg] + bz + cz);
          float nn = ftanh(acc[mt][4+jt][rg] + bn_ + r*(acc[mt][6+jt][rg] + cn));
          float hold = hin[(size_t)n*128 + j];
          float hv = (1.f-z)*nn + z*hold;
          hout[(size_t)n*128 + j] = hv;
          ts += hv; tq += hv*hv;
        }
      }
    }
    if (sumP){
      atomicAdd(&sumP[(blockIdx.x&63)*128 + j], ts);
      atomicAdd(&sqP [(blockIdx.x&63)*128 + j], tq);
    }
  }
}

// hf = relu(bn2(h)+skip), run-length pooled (batch sorted) + fused node count
__global__ void k_bn2_pool(const float* __restrict__ hfin, const float* __restrict__ h0,
                           const int* __restrict__ batch, const float* __restrict__ sc,
                           const float* __restrict__ sh, float* __restrict__ pool,
                           float* __restrict__ cntf, int N){
  int t=threadIdx.x, j=t&127, half=t>>7;
  int n0 = blockIdx.x*256 + half*128;
  float scv=sc[j], shv=sh[j];
  int curg=-1; float acc=0.f, cacc=0.f;
  for (int r=0;r<128;r++){
    int n=n0+r; if (n>=N) break;
    int g = batch[n];
    float v = fmaxf(hfin[(size_t)n*128+j]*scv+shv + h0[(size_t)n*128+j], 0.f);
    if (g!=curg){
      if (curg>=0){
        atomicAdd(&pool[curg*128+j], acc);
        if (j==0) atomicAdd(&cntf[curg], cacc);
      }
      curg=g; acc=0.f; cacc=0.f;
    }
    acc+=v; cacc+=1.f;
  }
  if (curg>=0){
    atomicAdd(&pool[curg*128+j], acc);
    if (j==0) atomicAdd(&cntf[curg], cacc);
  }
}

__global__ void k_head1(const float* __restrict__ pool, const float* __restrict__ cntf,
                        const float* __restrict__ W1cT, const float* __restrict__ b1,
                        float* __restrict__ t3, float* __restrict__ sum3, float* __restrict__ sq3){
  __shared__ float mean[128];
  int g=blockIdx.x, o=threadIdx.x;
  float inv = 1.0f/fmaxf(cntf[g],1.0f);
  mean[o] = pool[g*128+o]*inv;
  __syncthreads();
  float acc=0.f;
  for (int jj=0;jj<128;jj++) acc += mean[jj]*W1cT[jj*128+o];
  float v = acc + b1[o];
  t3[g*128+o]=v;
  atomicAdd(&sum3[o], v);
  atomicAdd(&sq3[o], v*v);
}

__global__ void k_head2(const float* __restrict__ t3, const float* __restrict__ sc,
                        const float* __restrict__ sh, const float* __restrict__ W2,
                        const float* __restrict__ b2, float* __restrict__ out){
  __shared__ float y[128];
  int g=blockIdx.x, o=threadIdx.x;
  float v = fmaxf(t3[g*128+o]*sc[o]+sh[o], 0.f);
  y[o]=v; __syncthreads();
  if (o<2){
    float acc=b2[o];
    for (int k=0;k<128;k++) acc += y[k]*W2[o*128+k];
    out[g*2+o]=acc;
  }
}

extern "C" void kernel_launch(void* const* d_in, const int* in_sizes, int n_in,
                              void* d_out, int out_size, void* d_ws, size_t ws_size,
                              hipStream_t stream){
  (void)n_in; (void)ws_size;
  const float* x    = (const float*)d_in[0];
  const int*   ei   = (const int*)d_in[1];
  const int*   batch= (const int*)d_in[2];
  const float* W_in = (const float*)d_in[3];
  const float* b_in = (const float*)d_in[4];
  const float* bn1_g= (const float*)d_in[5];
  const float* bn1_b= (const float*)d_in[6];
  const float* ggc  = (const float*)d_in[7];
  const float* wih  = (const float*)d_in[8];
  const float* whh  = (const float*)d_in[9];
  const float* bih  = (const float*)d_in[10];
  const float* bhh  = (const float*)d_in[11];
  const float* bn2_g= (const float*)d_in[12];
  const float* bn2_b= (const float*)d_in[13];
  const float* W1   = (const float*)d_in[14];
  const float* b1   = (const float*)d_in[15];
  const float* bn3_g= (const float*)d_in[16];
  const float* bn3_b= (const float*)d_in[17];
  const float* W2   = (const float*)d_in[18];
  const float* b2   = (const float*)d_in[19];
  float* out = (float*)d_out;

  int N = in_sizes[0]/128;
  int E = in_sizes[1]/2;
  int G = out_size/2;

  char* ws = (char*)d_ws;
  size_t off=0;
  auto alloc=[&](size_t bytes)->char*{
    char* p = ws+off; off = (off+bytes+255) & ~(size_t)255; return p;
  };
  float* buf0 = (float*)alloc((size_t)N*128*4);   // t -> s1/h1 -> s3/h3
  float* h0   = (float*)alloc((size_t)N*128*4);   // skip (persist)
  float* buf2 = (float*)alloc((size_t)N*128*4);   // s2/h2 -> s4/h4
  short* Bhi  = (short*)alloc((size_t)4*131072*2);
  short* Blo  = (short*)alloc((size_t)4*131072*2);
  float* Wq   = (float*)alloc((size_t)16384*4);
  float* W1cT = (float*)alloc((size_t)16384*4);
  int* rowptr = (int*)alloc((size_t)(N+1)*4);
  int* col    = (int*)alloc((size_t)E*4);
  int* bsum   = (int*)alloc((size_t)512*4);
  float* t3   = (float*)alloc((size_t)G*128*4);
  float* sc1 = (float*)alloc(512); float* sh1 = (float*)alloc(512);
  float* sc2 = (float*)alloc(512); float* sh2 = (float*)alloc(512);
  float* sc3 = (float*)alloc(512); float* sh3 = (float*)alloc(512);
  // --- zero region (contiguous) ---
  char* zstart = ws+off;
  int*   deg  = (int*)alloc((size_t)N*4);
  float* sumP1= (float*)alloc((size_t)64*128*4);
  float* sqP1 = (float*)alloc((size_t)64*128*4);
  float* sumP2= (float*)alloc((size_t)64*128*4);
  float* sqP2 = (float*)alloc((size_t)64*128*4);
  float* sum3 = (float*)alloc(512);
  float* sq3  = (float*)alloc(512);
  float* pool = (float*)alloc((size_t)G*128*4);
  float* cntf = (float*)alloc((size_t)G*4);
  char* zend = ws+off;
  int zwords = (int)((zend - zstart)/4);

  int nbScan  = (N+255)/256;     // 391 (<=512 for k_scan2)
  int gridN32 = (N+31)/32;       // 3125
  int gridAgg = (N*64+255)/256;

  k_zero<<<(zwords+255)/256,256,0,stream>>>((float*)zstart, zwords);
  k_prep<<<128,256,0,stream>>>(W_in, Wq, W1, W1cT);
  k_prepB<<<2048,256,0,stream>>>(ggc, wih, whh, Bhi, Blo);

  // CSR build
  k_hist<<<(E+255)/256,256,0,stream>>>(ei+E, deg, E);
  k_scan1<<<nbScan,256,0,stream>>>(deg, rowptr, bsum, N);
  k_scan2<<<1,512,0,stream>>>(bsum, nbScan, rowptr);
  k_scan3<<<nbScan,256,0,stream>>>(rowptr, bsum, N);
  k_fill<<<(E+255)/256,256,0,stream>>>(ei, deg, rowptr, col, E);

  // input GEMM + BN1
  k_gemm_in<<<gridN32,256,0,stream>>>(x, Wq, b_in, buf0, sumP1, sqP1, N);
  k_bn_fin<<<1,128,0,stream>>>(sumP1, sqP1, 64, 1.0f/(float)N, bn1_g, bn1_b, sc1, sh1);
  k_apply_bn1<<<(N*128/4+255)/256,256,0,stream>>>((const float4*)buf0, sc1, sh1, (float4*)h0, N*128/4);

  // 4 GRU steps: agg into s-buffer, MFMA GRU writes h in-place over s rows
  k_agg<<<gridAgg,256,0,stream>>>(h0,   buf0, rowptr, col, N);
  k_gru_mfma<<<gridN32,256,0,stream>>>(buf0, h0,   buf0, Bhi+0*131072, Blo+0*131072, bih, bhh, N, nullptr, nullptr);
  k_agg<<<gridAgg,256,0,stream>>>(buf0, buf2, rowptr, col, N);
  k_gru_mfma<<<gridN32,256,0,stream>>>(buf2, buf0, buf2, Bhi+1*131072, Blo+1*131072, bih, bhh, N, nullptr, nullptr);
  k_agg<<<gridAgg,256,0,stream>>>(buf2, buf0, rowptr, col, N);
  k_gru_mfma<<<gridN32,256,0,stream>>>(buf0, buf2, buf0, Bhi+2*131072, Blo+2*131072, bih, bhh, N, nullptr, nullptr);
  k_agg<<<gridAgg,256,0,stream>>>(buf0, buf2, rowptr, col, N);
  k_gru_mfma<<<gridN32,256,0,stream>>>(buf2, buf0, buf2, Bhi+3*131072, Blo+3*131072, bih, bhh, N, sumP2, sqP2);

  // BN2 + skip + pool (+count), head
  k_bn_fin<<<1,128,0,stream>>>(sumP2, sqP2, 64, 1.0f/(float)N, bn2_g, bn2_b, sc2, sh2);
  k_bn2_pool<<<(N+255)/256,256,0,stream>>>(buf2, h0, batch, sc2, sh2, pool, cntf, N);
  k_head1<<<G,128,0,stream>>>(pool, cntf, W1cT, b1, t3, sum3, sq3);
  k_bn_fin<<<1,128,0,stream>>>(sum3, sq3, 1, 1.0f/(float)G, bn3_g, bn3_b, sc3, sh3);
  k_head2<<<G,128,0,stream>>>(t3, sc3, sh3, W2, b2, out);
}

// Round 9
// 1448.804 us; speedup vs baseline: 1.8529x; 1.0313x over previous
//
#include <hip/hip_runtime.h>
#include <math.h>

// GNN: GatedGraphConv(4 steps) + BN/ReLU + mean-pool + MLP head.
// r9: split-bf16 MFMA GRU v2:
//  - skip structurally-zero B gate blocks (G3 for k<128, G2 for k>=128): -25% MFMA
//  - GRU 'hold' reconstructed from LDS (hi+lo), no scattered global re-reads
//  - outputs transposed through LDS -> coalesced float4 row stores
//    (r8 had 90MB WRITE vs 51MB ideal: 64B half-line dirty amplification)

#define EPSV 1e-5f

typedef __attribute__((ext_vector_type(8))) short bf16x8;
typedef __attribute__((ext_vector_type(4))) float f32x4;

__device__ __forceinline__ float fsig(float x){
  return 1.0f/(1.0f+__expf(-x));
}
__device__ __forceinline__ float ftanh(float x){
  float ax = fabsf(x);
  float e = __expf(-2.0f*ax);
  float r = (1.0f-e)/(1.0f+e);
  return copysignf(r, x);
}
__device__ __forceinline__ unsigned short bf16rne(float x){
  unsigned u = __float_as_uint(x);
  unsigned r = (u + 0x7FFFu + ((u>>16)&1u)) >> 16;
  return (unsigned short)r;
}
__device__ __forceinline__ float bf16tof(unsigned short h){
  return __uint_as_float(((unsigned)h)<<16);
}

__global__ void k_zero(float* __restrict__ p, int n){
  int i = blockIdx.x*256+threadIdx.x;
  if (i<n) p[i]=0.0f;
}

// Wq (input GEMM quad layout) + W1cT (head). grid 128.
__global__ void k_prep(const float* __restrict__ Win, float* __restrict__ Wq,
                       const float* __restrict__ W1, float* __restrict__ W1cT){
  int i = blockIdx.x*256+threadIdx.x;
  if (i < 16384){
    int k=i>>7, j=i&127;
    Wq[(k>>2)*512 + j*4 + (k&3)] = Win[j*128+k];
  } else if (i < 32768){
    int r=i-16384; int j=r>>7, o=r&127;
    W1cT[j*128+o] = W1[o*256+j] + W1[o*256+128+j];
  }
}

// Build B (4 steps x 256k x 512c) as bf16 hi/lo in MFMA fragment order:
//   off = st*131072 + ((k>>5)*512 + c)*32 + (k&31)   [shorts]
__global__ void k_prepB(const float* __restrict__ ggc, const float* __restrict__ wih,
                        const float* __restrict__ whh,
                        short* __restrict__ Bhi, short* __restrict__ Blo){
  int i = blockIdx.x*256+threadIdx.x;      // [0, 524288)
  int st = i>>17;
  int r  = i&131071;
  int k  = r>>9;
  int c  = r&511;
  int gr = c>>7, j = c&127;
  float val = 0.f;
  if (k<128){
    if (gr<3){
      const float* g = ggc + st*16384 + k*128;
      const float* w = wih + (gr*128+j)*128;
      float acc=0.f;
      for (int m=0;m<128;m++) acc += g[m]*w[m];
      val = acc;
    }
  } else {
    int kh = k-128;
    if (gr!=2){
      int gate = (gr==3)?2:gr;
      val = whh[(gate*128+j)*128 + kh];
    }
  }
  unsigned short h = bf16rne(val);
  unsigned short lo = bf16rne(val - bf16tof(h));
  size_t off = (size_t)st*131072 + ((size_t)(k>>5)*512 + (size_t)c)*32 + (size_t)(k&31);
  Bhi[off]=(short)h; Blo[off]=(short)lo;
}

// t = x @ W_in^T + b_in, fused BN1 column stat partials (64-way)
__global__ __launch_bounds__(256,2) void k_gemm_in(
    const float* __restrict__ x, const float* __restrict__ Wq, const float* __restrict__ bin,
    float* __restrict__ X, float* __restrict__ sumP, float* __restrict__ sqP, int N)
{
  __shared__ __align__(16) float xl[32][128];
  __shared__ float red[2][128];
  int t=threadIdx.x;
  int nbase = blockIdx.x*32;
  for (int it=0; it<4; ++it){
    int f4 = it*256+t;
    int n = f4>>5; int k=(f4&31)*4;
    int gn=nbase+n;
    float4 v = make_float4(0.f,0.f,0.f,0.f);
    if (gn<N) v = *(const float4*)&x[(size_t)gn*128+k];
    *(float4*)&xl[n][k]=v;
  }
  __syncthreads();
  int j=t&127, half=t>>7, nb=half*16;
  float acc[16];
  #pragma unroll
  for (int q=0;q<16;q++) acc[q]=0.f;
  for (int k=0;k<128;k+=4){
    float4 w = *(const float4*)&Wq[(k>>2)*512 + j*4];
    #pragma unroll
    for (int q=0;q<16;q++){
      float4 xv = *(const float4*)&xl[nb+q][k];
      acc[q] += xv.x*w.x + xv.y*w.y + xv.z*w.z + xv.w*w.w;
    }
  }
  float bv = bin[j];
  float ts=0.f, tq=0.f;
  #pragma unroll
  for (int q=0;q<16;q++){
    int n=nbase+nb+q;
    if (n<N){
      float tv=acc[q]+bv;
      X[(size_t)n*128+j]=tv;
      ts+=tv; tq+=tv*tv;
    }
  }
  int p = (blockIdx.x&63)*128+j;
  red[half][j]=ts; __syncthreads();
  if (half==0) atomicAdd(&sumP[p], red[0][j]+red[1][j]);
  __syncthreads();
  red[half][j]=tq; __syncthreads();
  if (half==0) atomicAdd(&sqP[p], red[0][j]+red[1][j]);
}

__global__ void k_bn_fin(const float* __restrict__ sumP, const float* __restrict__ sqP, int P, float invcnt,
                         const float* __restrict__ g, const float* __restrict__ b,
                         float* __restrict__ sc, float* __restrict__ sh){
  int j = threadIdx.x;
  if (j>=128) return;
  float s=0.f,q=0.f;
  for (int p=0;p<P;p++){ s+=sumP[p*128+j]; q+=sqP[p*128+j]; }
  float mu = s*invcnt;
  float var = fmaxf(q*invcnt - mu*mu, 0.f);
  float scale = g[j]*rsqrtf(var+EPSV);
  sc[j]=scale; sh[j]=b[j]-mu*scale;
}

__global__ void k_apply_bn1(const float4* __restrict__ X, const float* __restrict__ sc,
                            const float* __restrict__ sh, float4* __restrict__ h0, int total4){
  int i = blockIdx.x*256+threadIdx.x;
  if (i>=total4) return;
  float4 t = X[i];
  int j0 = (i*4)&127;
  float4 s = *(const float4*)&sc[j0];
  float4 b = *(const float4*)&sh[j0];
  float4 o;
  o.x = fmaxf(t.x*s.x+b.x, 0.f);
  o.y = fmaxf(t.y*s.y+b.y, 0.f);
  o.z = fmaxf(t.z*s.z+b.z, 0.f);
  o.w = fmaxf(t.w*s.w+b.w, 0.f);
  h0[i]=o;
}

// ---- CSR build (rows = dst, cols = src) ----
__global__ void k_hist(const int* __restrict__ dst, int* __restrict__ deg, int E){
  int e = blockIdx.x*256+threadIdx.x;
  if (e<E) atomicAdd(&deg[dst[e]], 1);
}
__global__ void k_scan1(const int* __restrict__ deg, int* __restrict__ rowptr, int* __restrict__ bsum, int N){
  __shared__ int tmp[256];
  int t=threadIdx.x; int n=blockIdx.x*256+t;
  int v = (n<N)?deg[n]:0;
  tmp[t]=v;
  __syncthreads();
  for (int o=1;o<256;o<<=1){
    int add = (t>=o)? tmp[t-o] : 0;
    __syncthreads();
    tmp[t]+=add;
    __syncthreads();
  }
  if (n<N) rowptr[n+1]=tmp[t];
  if (t==255) bsum[blockIdx.x]=tmp[255];
}
__global__ void k_scan2(int* bsum, int nb, int* rowptr){
  __shared__ int tmp[512];
  int t=threadIdx.x;
  int v = (t<nb)? bsum[t] : 0;
  tmp[t]=v; __syncthreads();
  for (int o=1;o<512;o<<=1){
    int add = (t>=o)? tmp[t-o] : 0;
    __syncthreads();
    tmp[t]+=add;
    __syncthreads();
  }
  if (t<nb) bsum[t]=tmp[t]-v;
  if (t==0) rowptr[0]=0;
}
__global__ void k_scan3(int* rowptr, const int* __restrict__ bsum, int N){
  int n = blockIdx.x*256+threadIdx.x;
  if (n<N) rowptr[n+1] += bsum[blockIdx.x];
}
__global__ void k_fill(const int* __restrict__ ei, int* __restrict__ deg,
                       const int* __restrict__ rowptr, int* __restrict__ col, int E){
  int e = blockIdx.x*256+threadIdx.x;
  if (e<E){
    int d = ei[E+e];
    int old = atomicSub(&deg[d],1);
    col[rowptr[d] + old - 1] = ei[e];
  }
}

// s[n] = sum_{e in row n} h[col[e]]  — one wave per node, 4 rows in flight
__global__ __launch_bounds__(256,8) void k_agg(
    const float* __restrict__ h, float* __restrict__ s,
    const int* __restrict__ rowptr, const int* __restrict__ col, int N)
{
  int wave = (blockIdx.x*256+threadIdx.x)>>6;
  int lane = threadIdx.x&63;
  if (wave>=N) return;
  int e = rowptr[wave], e1 = rowptr[wave+1];
  float2 a0=make_float2(0.f,0.f), a1=a0, a2=a0, a3=a0;
  for (; e+3<e1; e+=4){
    int c0=col[e],c1=col[e+1],c2=col[e+2],c3=col[e+3];
    float2 v0 = *(const float2*)&h[(size_t)c0*128+lane*2];
    float2 v1 = *(const float2*)&h[(size_t)c1*128+lane*2];
    float2 v2 = *(const float2*)&h[(size_t)c2*128+lane*2];
    float2 v3 = *(const float2*)&h[(size_t)c3*128+lane*2];
    a0.x+=v0.x; a0.y+=v0.y; a1.x+=v1.x; a1.y+=v1.y;
    a2.x+=v2.x; a2.y+=v2.y; a3.x+=v3.x; a3.y+=v3.y;
  }
  for (; e<e1; e++){
    int c0=col[e];
    float2 v0 = *(const float2*)&h[(size_t)c0*128+lane*2];
    a0.x+=v0.x; a0.y+=v0.y;
  }
  float2 r;
  r.x=(a0.x+a1.x)+(a2.x+a3.x);
  r.y=(a0.y+a1.y)+(a2.y+a3.y);
  *(float2*)&s[(size_t)wave*128+lane*2]=r;
}

// Split-bf16 MFMA GRU v2. Block = 32 nodes, 4 waves.
// A = [s|h] rows staged in LDS (bf16 hi/lo, XOR-swizzled 16B granules).
// Zero gate blocks skipped: kc<4 -> gates {r,z,i_n}; kc>=4 -> {r,z,h_n}.
// hold reconstructed from LDS; outputs transposed via LDS -> float4 stores.
__global__ __launch_bounds__(256,2) void k_gru_mfma(
    const float* __restrict__ s, const float* __restrict__ hin, float* __restrict__ hout,
    const short* __restrict__ Bhi, const short* __restrict__ Blo,
    const float* __restrict__ bih, const float* __restrict__ bhh, int N,
    float* __restrict__ sumP, float* __restrict__ sqP)
{
  __shared__ __align__(16) short Abuf[2*32*256];   // 32 KB: Ahi | Alo; reused for out-transpose
  short* Ahi = Abuf;
  short* Alo = Abuf + 32*256;
  int t = threadIdx.x;
  int nbase = blockIdx.x*32;

  // ---- stage A: 32 rows x 256 k (k<128 from s, k>=128 from h), hi/lo split ----
  for (int it=0; it<8; ++it){
    int f4 = it*256 + t;            // [0,2048) float4 chunks
    int row = f4>>6;                // 64 float4 per row
    int c4  = f4&63;                // k = c4*4
    int k   = c4*4;
    int n   = nbase + row;
    float4 v = make_float4(0.f,0.f,0.f,0.f);
    if (n < N){
      const float* src = (k<128) ? &s[(size_t)n*128 + k] : &hin[(size_t)n*128 + (k-128)];
      v = *(const float4*)src;
    }
    unsigned short h0=bf16rne(v.x), h1=bf16rne(v.y), h2=bf16rne(v.z), h3=bf16rne(v.w);
    unsigned short l0=bf16rne(v.x-bf16tof(h0)), l1=bf16rne(v.y-bf16tof(h1));
    unsigned short l2=bf16rne(v.z-bf16tof(h2)), l3=bf16rne(v.w-bf16tof(h3));
    int g = c4>>1, half = c4&1;
    int gs = g ^ (row&7);
    int off = row*256 + gs*8 + half*4;     // shorts
    uint2 H; H.x = (unsigned)h0 | ((unsigned)h1<<16); H.y = (unsigned)h2 | ((unsigned)h3<<16);
    uint2 L; L.x = (unsigned)l0 | ((unsigned)l1<<16); L.y = (unsigned)l2 | ((unsigned)l3<<16);
    *(uint2*)&Ahi[off] = H;
    *(uint2*)&Alo[off] = L;
  }
  __syncthreads();

  int wv = t>>6, l = t&63;
  int lj = l&15, lk = l>>4;

  f32x4 acc[2][8];
  #pragma unroll
  for (int mt=0; mt<2; ++mt)
    #pragma unroll
    for (int nt=0; nt<8; ++nt)
      acc[mt][nt] = (f32x4){0.f,0.f,0.f,0.f};

#define DO_GR(GR_) { \
    _Pragma("unroll") \
    for (int jt=0; jt<2; ++jt){ \
      int c  = (GR_)*128 + wv*32 + jt*16 + lj; \
      size_t boff = ((size_t)kc*512 + (size_t)c)*32 + (size_t)lk*8; \
      bf16x8 b_hi = *(const bf16x8*)&Bhi[boff]; \
      bf16x8 b_lo = *(const bf16x8*)&Blo[boff]; \
      acc[0][(GR_)*2+jt] = __builtin_amdgcn_mfma_f32_16x16x32_bf16(a_hi[0], b_hi, acc[0][(GR_)*2+jt], 0,0,0); \
      acc[1][(GR_)*2+jt] = __builtin_amdgcn_mfma_f32_16x16x32_bf16(a_hi[1], b_hi, acc[1][(GR_)*2+jt], 0,0,0); \
      acc[0][(GR_)*2+jt] = __builtin_amdgcn_mfma_f32_16x16x32_bf16(a_lo[0], b_hi, acc[0][(GR_)*2+jt], 0,0,0); \
      acc[1][(GR_)*2+jt] = __builtin_amdgcn_mfma_f32_16x16x32_bf16(a_lo[1], b_hi, acc[1][(GR_)*2+jt], 0,0,0); \
      acc[0][(GR_)*2+jt] = __builtin_amdgcn_mfma_f32_16x16x32_bf16(a_hi[0], b_lo, acc[0][(GR_)*2+jt], 0,0,0); \
      acc[1][(GR_)*2+jt] = __builtin_amdgcn_mfma_f32_16x16x32_bf16(a_hi[1], b_lo, acc[1][(GR_)*2+jt], 0,0,0); \
    } }

  for (int kc=0; kc<4; ++kc){      // k<128: s-part, gates {0:r, 1:z, 2:i_n}
    bf16x8 a_hi[2], a_lo[2];
    #pragma unroll
    for (int mt=0; mt<2; ++mt){
      int r = mt*16 + lj;
      int g = kc*4 + lk;
      int off = r*256 + ((g ^ (r&7))<<3);
      a_hi[mt] = *(bf16x8*)&Ahi[off];
      a_lo[mt] = *(bf16x8*)&Alo[off];
    }
    DO_GR(0) DO_GR(1) DO_GR(2)
  }
  for (int kc=4; kc<8; ++kc){      // k>=128: h-part, gates {0:r, 1:z, 3:h_n}
    bf16x8 a_hi[2], a_lo[2];
    #pragma unroll
    for (int mt=0; mt<2; ++mt){
      int r = mt*16 + lj;
      int g = kc*4 + lk;
      int off = r*256 + ((g ^ (r&7))<<3);
      a_hi[mt] = *(bf16x8*)&Ahi[off];
      a_lo[mt] = *(bf16x8*)&Alo[off];
    }
    DO_GR(0) DO_GR(1) DO_GR(3)
  }
#undef DO_GR

  // ---- hold from LDS (hi+lo reconstruction, ~2^-17 relative error) ----
  float holdv[2][2][4];
  #pragma unroll
  for (int jt=0; jt<2; ++jt){
    int j = wv*32 + jt*16 + lj;
    int g = 16 + (j>>3);
    int pos = j&7;
    #pragma unroll
    for (int mt=0; mt<2; ++mt){
      #pragma unroll
      for (int rg=0; rg<4; ++rg){
        int row = mt*16 + lk*4 + rg;
        int off = row*256 + ((g ^ (row&7))<<3) + pos;
        holdv[jt][mt][rg] = bf16tof((unsigned short)Ahi[off]) + bf16tof((unsigned short)Alo[off]);
      }
    }
  }

  // ---- GRU epilogue: G0=r, G1=z, G2=i_n, G3=h_n ----
  float hvv[2][2][4];
  #pragma unroll
  for (int jt=0; jt<2; ++jt){
    int j = wv*32 + jt*16 + lj;
    float br=bih[j], bz=bih[128+j], bn_=bih[256+j];
    float cr=bhh[j], cz=bhh[128+j], cn=bhh[256+j];
    float ts=0.f, tq=0.f;
    #pragma unroll
    for (int mt=0; mt<2; ++mt){
      #pragma unroll
      for (int rg=0; rg<4; ++rg){
        float r  = fsig(acc[mt][0+jt][rg] + br + cr);
        float z  = fsig(acc[mt][2+jt][rg] + bz + cz);
        float nn = ftanh(acc[mt][4+jt][rg] + bn_ + r*(acc[mt][6+jt][rg] + cn));
        float hv = (1.f-z)*nn + z*holdv[jt][mt][rg];
        hvv[jt][mt][rg] = hv;
        ts += hv; tq += hv*hv;
      }
    }
    if (sumP){
      atomicAdd(&sumP[(blockIdx.x&63)*128 + j], ts);
      atomicAdd(&sqP [(blockIdx.x&63)*128 + j], tq);
    }
  }

  // ---- transpose via LDS -> coalesced float4 row stores ----
  __syncthreads();                       // all LDS reads (A) done
  float* O = (float*)Abuf;               // [32][132] floats = 16.9 KB
  #pragma unroll
  for (int jt=0; jt<2; ++jt){
    int j = wv*32 + jt*16 + lj;
    #pragma unroll
    for (int mt=0; mt<2; ++mt){
      #pragma unroll
      for (int rg=0; rg<4; ++rg){
        int row = mt*16 + lk*4 + rg;
        O[row*132 + j] = hvv[jt][mt][rg];
      }
    }
  }
  __syncthreads();
  for (int it=0; it<4; ++it){
    int idx = it*256 + t;
    int row = idx>>5, c4 = idx&31;
    int n = nbase + row;
    if (n < N){
      *(float4*)&hout[(size_t)n*128 + c4*4] = *(float4*)&O[row*132 + c4*4];
    }
  }
}

// hf = relu(bn2(h)+skip), run-length pooled (batch sorted) + fused node count
__global__ void k_bn2_pool(const float* __restrict__ hfin, const float* __restrict__ h0,
                           const int* __restrict__ batch, const float* __restrict__ sc,
                           const float* __restrict__ sh, float* __restrict__ pool,
                           float* __restrict__ cntf, int N){
  int t=threadIdx.x, j=t&127, half=t>>7;
  int n0 = blockIdx.x*256 + half*128;
  float scv=sc[j], shv=sh[j];
  int curg=-1; float acc=0.f, cacc=0.f;
  for (int r=0;r<128;r++){
    int n=n0+r; if (n>=N) break;
    int g = batch[n];
    float v = fmaxf(hfin[(size_t)n*128+j]*scv+shv + h0[(size_t)n*128+j], 0.f);
    if (g!=curg){
      if (curg>=0){
        atomicAdd(&pool[curg*128+j], acc);
        if (j==0) atomicAdd(&cntf[curg], cacc);
      }
      curg=g; acc=0.f; cacc=0.f;
    }
    acc+=v; cacc+=1.f;
  }
  if (curg>=0){
    atomicAdd(&pool[curg*128+j], acc);
    if (j==0) atomicAdd(&cntf[curg], cacc);
  }
}

__global__ void k_head1(const float* __restrict__ pool, const float* __restrict__ cntf,
                        const float* __restrict__ W1cT, const float* __restrict__ b1,
                        float* __restrict__ t3, float* __restrict__ sum3, float* __restrict__ sq3){
  __shared__ float mean[128];
  int g=blockIdx.x, o=threadIdx.x;
  float inv = 1.0f/fmaxf(cntf[g],1.0f);
  mean[o] = pool[g*128+o]*inv;
  __syncthreads();
  float acc=0.f;
  for (int jj=0;jj<128;jj++) acc += mean[jj]*W1cT[jj*128+o];
  float v = acc + b1[o];
  t3[g*128+o]=v;
  atomicAdd(&sum3[o], v);
  atomicAdd(&sq3[o], v*v);
}

__global__ void k_head2(const float* __restrict__ t3, const float* __restrict__ sc,
                        const float* __restrict__ sh, const float* __restrict__ W2,
                        const float* __restrict__ b2, float* __restrict__ out){
  __shared__ float y[128];
  int g=blockIdx.x, o=threadIdx.x;
  float v = fmaxf(t3[g*128+o]*sc[o]+sh[o], 0.f);
  y[o]=v; __syncthreads();
  if (o<2){
    float acc=b2[o];
    for (int k=0;k<128;k++) acc += y[k]*W2[o*128+k];
    out[g*2+o]=acc;
  }
}

extern "C" void kernel_launch(void* const* d_in, const int* in_sizes, int n_in,
                              void* d_out, int out_size, void* d_ws, size_t ws_size,
                              hipStream_t stream){
  (void)n_in; (void)ws_size;
  const float* x    = (const float*)d_in[0];
  const int*   ei   = (const int*)d_in[1];
  const int*   batch= (const int*)d_in[2];
  const float* W_in = (const float*)d_in[3];
  const float* b_in = (const float*)d_in[4];
  const float* bn1_g= (const float*)d_in[5];
  const float* bn1_b= (const float*)d_in[6];
  const float* ggc  = (const float*)d_in[7];
  const float* wih  = (const float*)d_in[8];
  const float* whh  = (const float*)d_in[9];
  const float* bih  = (const float*)d_in[10];
  const float* bhh  = (const float*)d_in[11];
  const float* bn2_g= (const float*)d_in[12];
  const float* bn2_b= (const float*)d_in[13];
  const float* W1   = (const float*)d_in[14];
  const float* b1   = (const float*)d_in[15];
  const float* bn3_g= (const float*)d_in[16];
  const float* bn3_b= (const float*)d_in[17];
  const float* W2   = (const float*)d_in[18];
  const float* b2   = (const float*)d_in[19];
  float* out = (float*)d_out;

  int N = in_sizes[0]/128;
  int E = in_sizes[1]/2;
  int G = out_size/2;

  char* ws = (char*)d_ws;
  size_t off=0;
  auto alloc=[&](size_t bytes)->char*{
    char* p = ws+off; off = (off+bytes+255) & ~(size_t)255; return p;
  };
  float* buf0 = (float*)alloc((size_t)N*128*4);   // t -> s1/h1 -> s3/h3
  float* h0   = (float*)alloc((size_t)N*128*4);   // skip (persist)
  float* buf2 = (float*)alloc((size_t)N*128*4);   // s2/h2 -> s4/h4
  short* Bhi  = (short*)alloc((size_t)4*131072*2);
  short* Blo  = (short*)alloc((size_t)4*131072*2);
  float* Wq   = (float*)alloc((size_t)16384*4);
  float* W1cT = (float*)alloc((size_t)16384*4);
  int* rowptr = (int*)alloc((size_t)(N+1)*4);
  int* col    = (int*)alloc((size_t)E*4);
  int* bsum   = (int*)alloc((size_t)512*4);
  float* t3   = (float*)alloc((size_t)G*128*4);
  float* sc1 = (float*)alloc(512); float* sh1 = (float*)alloc(512);
  float* sc2 = (float*)alloc(512); float* sh2 = (float*)alloc(512);
  float* sc3 = (float*)alloc(512); float* sh3 = (float*)alloc(512);
  // --- zero region (contiguous) ---
  char* zstart = ws+off;
  int*   deg  = (int*)alloc((size_t)N*4);
  float* sumP1= (float*)alloc((size_t)64*128*4);
  float* sqP1 = (float*)alloc((size_t)64*128*4);
  float* sumP2= (float*)alloc((size_t)64*128*4);
  float* sqP2 = (float*)alloc((size_t)64*128*4);
  float* sum3 = (float*)alloc(512);
  float* sq3  = (float*)alloc(512);
  float* pool = (float*)alloc((size_t)G*128*4);
  float* cntf = (float*)alloc((size_t)G*4);
  char* zend = ws+off;
  int zwords = (int)((zend - zstart)/4);

  int nbScan  = (N+255)/256;     // 391 (<=512 for k_scan2)
  int gridN32 = (N+31)/32;       // 3125
  int gridAgg = (N*64+255)/256;

  k_zero<<<(zwords+255)/256,256,0,stream>>>((float*)zstart, zwords);
  k_prep<<<128,256,0,stream>>>(W_in, Wq, W1, W1cT);
  k_prepB<<<2048,256,0,stream>>>(ggc, wih, whh, Bhi, Blo);

  // CSR build
  k_hist<<<(E+255)/256,256,0,stream>>>(ei+E, deg, E);
  k_scan1<<<nbScan,256,0,stream>>>(deg, rowptr, bsum, N);
  k_scan2<<<1,512,0,stream>>>(bsum, nbScan, rowptr);
  k_scan3<<<nbScan,256,0,stream>>>(rowptr, bsum, N);
  k_fill<<<(E+255)/256,256,0,stream>>>(ei, deg, rowptr, col, E);

  // input GEMM + BN1
  k_gemm_in<<<gridN32,256,0,stream>>>(x, Wq, b_in, buf0, sumP1, sqP1, N);
  k_bn_fin<<<1,128,0,stream>>>(sumP1, sqP1, 64, 1.0f/(float)N, bn1_g, bn1_b, sc1, sh1);
  k_apply_bn1<<<(N*128/4+255)/256,256,0,stream>>>((const float4*)buf0, sc1, sh1, (float4*)h0, N*128/4);

  // 4 GRU steps: agg into s-buffer, MFMA GRU writes h in-place over s rows
  k_agg<<<gridAgg,256,0,stream>>>(h0,   buf0, rowptr, col, N);
  k_gru_mfma<<<gridN32,256,0,stream>>>(buf0, h0,   buf0, Bhi+0*131072, Blo+0*131072, bih, bhh, N, nullptr, nullptr);
  k_agg<<<gridAgg,256,0,stream>>>(buf0, buf2, rowptr, col, N);
  k_gru_mfma<<<gridN32,256,0,stream>>>(buf2, buf0, buf2, Bhi+1*131072, Blo+1*131072, bih, bhh, N, nullptr, nullptr);
  k_agg<<<gridAgg,256,0,stream>>>(buf2, buf0, rowptr, col, N);
  k_gru_mfma<<<gridN32,256,0,stream>>>(buf0, buf2, buf0, Bhi+2*131072, Blo+2*131072, bih, bhh, N, nullptr, nullptr);
  k_agg<<<gridAgg,256,0,stream>>>(buf0, buf2, rowptr, col, N);
  k_gru_mfma<<<gridN32,256,0,stream>>>(buf2, buf0, buf2, Bhi+3*131072, Blo+3*131072, bih, bhh, N, sumP2, sqP2);

  // BN2 + skip + pool (+count), head
  k_bn_fin<<<1,128,0,stream>>>(sumP2, sqP2, 64, 1.0f/(float)N, bn2_g, bn2_b, sc2, sh2);
  k_bn2_pool<<<(N+255)/256,256,0,stream>>>(buf2, h0, batch, sc2, sh2, pool, cntf, N);
  k_head1<<<G,128,0,stream>>>(pool, cntf, W1cT, b1, t3, sum3, sq3);
  k_bn_fin<<<1,128,0,stream>>>(sum3, sq3, 1, 1.0f/(float)G, bn3_g, bn3_b, sc3, sh3);
  k_head2<<<G,128,0,stream>>>(t3, sc3, sh3, W2, b2, out);
}

// Round 10
// 1378.297 us; speedup vs baseline: 1.9476x; 1.0512x over previous
//
#include <hip/hip_runtime.h>
#include <math.h>

// GNN: GatedGraphConv(4 steps) + BN/ReLU + mean-pool + MLP head.
// r10: MFMA GRU v3 — 8 waves x 512 threads per 32-node block, 16 cols/wave,
// acc[2 mt][4 gates] (=32 VGPR) with separate i_n/h_n accumulators.
// r9 was latency-bound at 38% occupancy with spill (VGPR 60 < 64-reg acc,
// +20MB scratch writes); halving the per-wave tile cuts live regs ~150->~110
// -> no spill, ~4 waves/SIMD to cover the B-fragment L2 latency.

#define EPSV 1e-5f

typedef __attribute__((ext_vector_type(8))) short bf16x8;
typedef __attribute__((ext_vector_type(4))) float f32x4;

__device__ __forceinline__ float fsig(float x){
  return 1.0f/(1.0f+__expf(-x));
}
__device__ __forceinline__ float ftanh(float x){
  float ax = fabsf(x);
  float e = __expf(-2.0f*ax);
  float r = (1.0f-e)/(1.0f+e);
  return copysignf(r, x);
}
__device__ __forceinline__ unsigned short bf16rne(float x){
  unsigned u = __float_as_uint(x);
  unsigned r = (u + 0x7FFFu + ((u>>16)&1u)) >> 16;
  return (unsigned short)r;
}
__device__ __forceinline__ float bf16tof(unsigned short h){
  return __uint_as_float(((unsigned)h)<<16);
}

__global__ void k_zero(float* __restrict__ p, int n){
  int i = blockIdx.x*256+threadIdx.x;
  if (i<n) p[i]=0.0f;
}

// Wq (input GEMM quad layout) + W1cT (head). grid 128.
__global__ void k_prep(const float* __restrict__ Win, float* __restrict__ Wq,
                       const float* __restrict__ W1, float* __restrict__ W1cT){
  int i = blockIdx.x*256+threadIdx.x;
  if (i < 16384){
    int k=i>>7, j=i&127;
    Wq[(k>>2)*512 + j*4 + (k&3)] = Win[j*128+k];
  } else if (i < 32768){
    int r=i-16384; int j=r>>7, o=r&127;
    W1cT[j*128+o] = W1[o*256+j] + W1[o*256+128+j];
  }
}

// Build B (4 steps x 256k x 512c) as bf16 hi/lo in MFMA fragment order:
//   off = st*131072 + ((k>>5)*512 + c)*32 + (k&31)   [shorts]
__global__ void k_prepB(const float* __restrict__ ggc, const float* __restrict__ wih,
                        const float* __restrict__ whh,
                        short* __restrict__ Bhi, short* __restrict__ Blo){
  int i = blockIdx.x*256+threadIdx.x;      // [0, 524288)
  int st = i>>17;
  int r  = i&131071;
  int k  = r>>9;
  int c  = r&511;
  int gr = c>>7, j = c&127;
  float val = 0.f;
  if (k<128){
    if (gr<3){
      const float* g = ggc + st*16384 + k*128;
      const float* w = wih + (gr*128+j)*128;
      float acc=0.f;
      for (int m=0;m<128;m++) acc += g[m]*w[m];
      val = acc;
    }
  } else {
    int kh = k-128;
    if (gr!=2){
      int gate = (gr==3)?2:gr;
      val = whh[(gate*128+j)*128 + kh];
    }
  }
  unsigned short h = bf16rne(val);
  unsigned short lo = bf16rne(val - bf16tof(h));
  size_t off = (size_t)st*131072 + ((size_t)(k>>5)*512 + (size_t)c)*32 + (size_t)(k&31);
  Bhi[off]=(short)h; Blo[off]=(short)lo;
}

// t = x @ W_in^T + b_in, fused BN1 column stat partials (64-way)
__global__ __launch_bounds__(256,2) void k_gemm_in(
    const float* __restrict__ x, const float* __restrict__ Wq, const float* __restrict__ bin,
    float* __restrict__ X, float* __restrict__ sumP, float* __restrict__ sqP, int N)
{
  __shared__ __align__(16) float xl[32][128];
  __shared__ float red[2][128];
  int t=threadIdx.x;
  int nbase = blockIdx.x*32;
  for (int it=0; it<4; ++it){
    int f4 = it*256+t;
    int n = f4>>5; int k=(f4&31)*4;
    int gn=nbase+n;
    float4 v = make_float4(0.f,0.f,0.f,0.f);
    if (gn<N) v = *(const float4*)&x[(size_t)gn*128+k];
    *(float4*)&xl[n][k]=v;
  }
  __syncthreads();
  int j=t&127, half=t>>7, nb=half*16;
  float acc[16];
  #pragma unroll
  for (int q=0;q<16;q++) acc[q]=0.f;
  for (int k=0;k<128;k+=4){
    float4 w = *(const float4*)&Wq[(k>>2)*512 + j*4];
    #pragma unroll
    for (int q=0;q<16;q++){
      float4 xv = *(const float4*)&xl[nb+q][k];
      acc[q] += xv.x*w.x + xv.y*w.y + xv.z*w.z + xv.w*w.w;
    }
  }
  float bv = bin[j];
  float ts=0.f, tq=0.f;
  #pragma unroll
  for (int q=0;q<16;q++){
    int n=nbase+nb+q;
    if (n<N){
      float tv=acc[q]+bv;
      X[(size_t)n*128+j]=tv;
      ts+=tv; tq+=tv*tv;
    }
  }
  int p = (blockIdx.x&63)*128+j;
  red[half][j]=ts; __syncthreads();
  if (half==0) atomicAdd(&sumP[p], red[0][j]+red[1][j]);
  __syncthreads();
  red[half][j]=tq; __syncthreads();
  if (half==0) atomicAdd(&sqP[p], red[0][j]+red[1][j]);
}

__global__ void k_bn_fin(const float* __restrict__ sumP, const float* __restrict__ sqP, int P, float invcnt,
                         const float* __restrict__ g, const float* __restrict__ b,
                         float* __restrict__ sc, float* __restrict__ sh){
  int j = threadIdx.x;
  if (j>=128) return;
  float s=0.f,q=0.f;
  for (int p=0;p<P;p++){ s+=sumP[p*128+j]; q+=sqP[p*128+j]; }
  float mu = s*invcnt;
  float var = fmaxf(q*invcnt - mu*mu, 0.f);
  float scale = g[j]*rsqrtf(var+EPSV);
  sc[j]=scale; sh[j]=b[j]-mu*scale;
}

__global__ void k_apply_bn1(const float4* __restrict__ X, const float* __restrict__ sc,
                            const float* __restrict__ sh, float4* __restrict__ h0, int total4){
  int i = blockIdx.x*256+threadIdx.x;
  if (i>=total4) return;
  float4 t = X[i];
  int j0 = (i*4)&127;
  float4 s = *(const float4*)&sc[j0];
  float4 b = *(const float4*)&sh[j0];
  float4 o;
  o.x = fmaxf(t.x*s.x+b.x, 0.f);
  o.y = fmaxf(t.y*s.y+b.y, 0.f);
  o.z = fmaxf(t.z*s.z+b.z, 0.f);
  o.w = fmaxf(t.w*s.w+b.w, 0.f);
  h0[i]=o;
}

// ---- CSR build (rows = dst, cols = src) ----
__global__ void k_hist(const int* __restrict__ dst, int* __restrict__ deg, int E){
  int e = blockIdx.x*256+threadIdx.x;
  if (e<E) atomicAdd(&deg[dst[e]], 1);
}
__global__ void k_scan1(const int* __restrict__ deg, int* __restrict__ rowptr, int* __restrict__ bsum, int N){
  __shared__ int tmp[256];
  int t=threadIdx.x; int n=blockIdx.x*256+t;
  int v = (n<N)?deg[n]:0;
  tmp[t]=v;
  __syncthreads();
  for (int o=1;o<256;o<<=1){
    int add = (t>=o)? tmp[t-o] : 0;
    __syncthreads();
    tmp[t]+=add;
    __syncthreads();
  }
  if (n<N) rowptr[n+1]=tmp[t];
  if (t==255) bsum[blockIdx.x]=tmp[255];
}
__global__ void k_scan2(int* bsum, int nb, int* rowptr){
  __shared__ int tmp[512];
  int t=threadIdx.x;
  int v = (t<nb)? bsum[t] : 0;
  tmp[t]=v; __syncthreads();
  for (int o=1;o<512;o<<=1){
    int add = (t>=o)? tmp[t-o] : 0;
    __syncthreads();
    tmp[t]+=add;
    __syncthreads();
  }
  if (t<nb) bsum[t]=tmp[t]-v;
  if (t==0) rowptr[0]=0;
}
__global__ void k_scan3(int* rowptr, const int* __restrict__ bsum, int N){
  int n = blockIdx.x*256+threadIdx.x;
  if (n<N) rowptr[n+1] += bsum[blockIdx.x];
}
__global__ void k_fill(const int* __restrict__ ei, int* __restrict__ deg,
                       const int* __restrict__ rowptr, int* __restrict__ col, int E){
  int e = blockIdx.x*256+threadIdx.x;
  if (e<E){
    int d = ei[E+e];
    int old = atomicSub(&deg[d],1);
    col[rowptr[d] + old - 1] = ei[e];
  }
}

// s[n] = sum_{e in row n} h[col[e]]  — one wave per node, 4 rows in flight
__global__ __launch_bounds__(256,8) void k_agg(
    const float* __restrict__ h, float* __restrict__ s,
    const int* __restrict__ rowptr, const int* __restrict__ col, int N)
{
  int wave = (blockIdx.x*256+threadIdx.x)>>6;
  int lane = threadIdx.x&63;
  if (wave>=N) return;
  int e = rowptr[wave], e1 = rowptr[wave+1];
  float2 a0=make_float2(0.f,0.f), a1=a0, a2=a0, a3=a0;
  for (; e+3<e1; e+=4){
    int c0=col[e],c1=col[e+1],c2=col[e+2],c3=col[e+3];
    float2 v0 = *(const float2*)&h[(size_t)c0*128+lane*2];
    float2 v1 = *(const float2*)&h[(size_t)c1*128+lane*2];
    float2 v2 = *(const float2*)&h[(size_t)c2*128+lane*2];
    float2 v3 = *(const float2*)&h[(size_t)c3*128+lane*2];
    a0.x+=v0.x; a0.y+=v0.y; a1.x+=v1.x; a1.y+=v1.y;
    a2.x+=v2.x; a2.y+=v2.y; a3.x+=v3.x; a3.y+=v3.y;
  }
  for (; e<e1; e++){
    int c0=col[e];
    float2 v0 = *(const float2*)&h[(size_t)c0*128+lane*2];
    a0.x+=v0.x; a0.y+=v0.y;
  }
  float2 r;
  r.x=(a0.x+a1.x)+(a2.x+a3.x);
  r.y=(a0.y+a1.y)+(a2.y+a3.y);
  *(float2*)&s[(size_t)wave*128+lane*2]=r;
}

// Split-bf16 MFMA GRU v3. Block = 32 nodes, 8 waves (512 thr); wave owns 16 cols.
// acc[mt][gate]: gate 0=r, 1=z, 2=i_n, 3=h_n (separate accumulators).
// kc<4 (s-part): gates {r,z,i_n}; kc>=4 (h-part): gates {r,z,h_n}.
// hold from LDS (hi+lo); outputs transposed via LDS -> coalesced float4 stores.
__global__ __launch_bounds__(512,2) void k_gru_mfma(
    const float* __restrict__ s, const float* __restrict__ hin, float* __restrict__ hout,
    const short* __restrict__ Bhi, const short* __restrict__ Blo,
    const float* __restrict__ bih, const float* __restrict__ bhh, int N,
    float* __restrict__ sumP, float* __restrict__ sqP)
{
  __shared__ __align__(16) short Abuf[2*32*256];   // 32 KB: Ahi | Alo; reused for out-transpose
  short* Ahi = Abuf;
  short* Alo = Abuf + 32*256;
  int t = threadIdx.x;
  int nbase = blockIdx.x*32;

  // ---- stage A: 32 rows x 256 k (k<128 from s, k>=128 from h), hi/lo split ----
  for (int it=0; it<4; ++it){
    int f4 = it*512 + t;            // [0,2048) float4 chunks
    int row = f4>>6;                // 64 float4 per row
    int c4  = f4&63;                // k = c4*4
    int k   = c4*4;
    int n   = nbase + row;
    float4 v = make_float4(0.f,0.f,0.f,0.f);
    if (n < N){
      const float* src = (k<128) ? &s[(size_t)n*128 + k] : &hin[(size_t)n*128 + (k-128)];
      v = *(const float4*)src;
    }
    unsigned short h0=bf16rne(v.x), h1=bf16rne(v.y), h2=bf16rne(v.z), h3=bf16rne(v.w);
    unsigned short l0=bf16rne(v.x-bf16tof(h0)), l1=bf16rne(v.y-bf16tof(h1));
    unsigned short l2=bf16rne(v.z-bf16tof(h2)), l3=bf16rne(v.w-bf16tof(h3));
    int g = c4>>1, half = c4&1;
    int gs = g ^ (row&7);
    int off = row*256 + gs*8 + half*4;     // shorts
    uint2 H; H.x = (unsigned)h0 | ((unsigned)h1<<16); H.y = (unsigned)h2 | ((unsigned)h3<<16);
    uint2 L; L.x = (unsigned)l0 | ((unsigned)l1<<16); L.y = (unsigned)l2 | ((unsigned)l3<<16);
    *(uint2*)&Ahi[off] = H;
    *(uint2*)&Alo[off] = L;
  }
  __syncthreads();

  int wv = t>>6, l = t&63;
  int lj = l&15, lk = l>>4;

  f32x4 acc[2][4];   // [mt][gate: r,z,i_n,h_n]
  #pragma unroll
  for (int mt=0; mt<2; ++mt)
    #pragma unroll
    for (int gt=0; gt<4; ++gt)
      acc[mt][gt] = (f32x4){0.f,0.f,0.f,0.f};

#define DO_G(G_) { \
    int c  = (G_)*128 + wv*16 + lj; \
    size_t boff = ((size_t)kc*512 + (size_t)c)*32 + (size_t)lk*8; \
    bf16x8 b_hi = *(const bf16x8*)&Bhi[boff]; \
    bf16x8 b_lo = *(const bf16x8*)&Blo[boff]; \
    acc[0][G_] = __builtin_amdgcn_mfma_f32_16x16x32_bf16(a_hi[0], b_hi, acc[0][G_], 0,0,0); \
    acc[1][G_] = __builtin_amdgcn_mfma_f32_16x16x32_bf16(a_hi[1], b_hi, acc[1][G_], 0,0,0); \
    acc[0][G_] = __builtin_amdgcn_mfma_f32_16x16x32_bf16(a_lo[0], b_hi, acc[0][G_], 0,0,0); \
    acc[1][G_] = __builtin_amdgcn_mfma_f32_16x16x32_bf16(a_lo[1], b_hi, acc[1][G_], 0,0,0); \
    acc[0][G_] = __builtin_amdgcn_mfma_f32_16x16x32_bf16(a_hi[0], b_lo, acc[0][G_], 0,0,0); \
    acc[1][G_] = __builtin_amdgcn_mfma_f32_16x16x32_bf16(a_hi[1], b_lo, acc[1][G_], 0,0,0); \
  }

  for (int kc=0; kc<4; ++kc){      // k<128: s-part, gates {r, z, i_n}
    bf16x8 a_hi[2], a_lo[2];
    #pragma unroll
    for (int mt=0; mt<2; ++mt){
      int r = mt*16 + lj;
      int g = kc*4 + lk;
      int off = r*256 + ((g ^ (r&7))<<3);
      a_hi[mt] = *(bf16x8*)&Ahi[off];
      a_lo[mt] = *(bf16x8*)&Alo[off];
    }
    DO_G(0) DO_G(1) DO_G(2)
  }
  for (int kc=4; kc<8; ++kc){      // k>=128: h-part, gates {r, z, h_n}
    bf16x8 a_hi[2], a_lo[2];
    #pragma unroll
    for (int mt=0; mt<2; ++mt){
      int r = mt*16 + lj;
      int g = kc*4 + lk;
      int off = r*256 + ((g ^ (r&7))<<3);
      a_hi[mt] = *(bf16x8*)&Ahi[off];
      a_lo[mt] = *(bf16x8*)&Alo[off];
    }
    DO_G(0) DO_G(1) DO_G(3)
  }
#undef DO_G

  // ---- hold from LDS (hi+lo reconstruction) ----
  int j = wv*16 + lj;
  float holdv[2][4];
  {
    int g = 16 + (j>>3);
    int pos = j&7;
    #pragma unroll
    for (int mt=0; mt<2; ++mt){
      #pragma unroll
      for (int rg=0; rg<4; ++rg){
        int row = mt*16 + lk*4 + rg;
        int off = row*256 + ((g ^ (row&7))<<3) + pos;
        holdv[mt][rg] = bf16tof((unsigned short)Ahi[off]) + bf16tof((unsigned short)Alo[off]);
      }
    }
  }

  // ---- GRU epilogue ----
  float hvv[2][4];
  {
    float br=bih[j], bz=bih[128+j], bn_=bih[256+j];
    float cr=bhh[j], cz=bhh[128+j], cn=bhh[256+j];
    float ts=0.f, tq=0.f;
    #pragma unroll
    for (int mt=0; mt<2; ++mt){
      #pragma unroll
      for (int rg=0; rg<4; ++rg){
        float r  = fsig(acc[mt][0][rg] + br + cr);
        float z  = fsig(acc[mt][1][rg] + bz + cz);
        float nn = ftanh(acc[mt][2][rg] + bn_ + r*(acc[mt][3][rg] + cn));
        float hv = (1.f-z)*nn + z*holdv[mt][rg];
        hvv[mt][rg] = hv;
        ts += hv; tq += hv*hv;
      }
    }
    if (sumP){
      atomicAdd(&sumP[(blockIdx.x&63)*128 + j], ts);
      atomicAdd(&sqP [(blockIdx.x&63)*128 + j], tq);
    }
  }

  // ---- transpose via LDS -> coalesced float4 row stores ----
  __syncthreads();                       // all LDS reads (A, hold) done
  float* O = (float*)Abuf;               // [32][132] floats = 16.9 KB
  #pragma unroll
  for (int mt=0; mt<2; ++mt){
    #pragma unroll
    for (int rg=0; rg<4; ++rg){
      int row = mt*16 + lk*4 + rg;
      O[row*132 + j] = hvv[mt][rg];
    }
  }
  __syncthreads();
  for (int it=0; it<2; ++it){
    int idx = it*512 + t;
    int row = idx>>5, c4 = idx&31;
    int n = nbase + row;
    if (n < N){
      *(float4*)&hout[(size_t)n*128 + c4*4] = *(float4*)&O[row*132 + c4*4];
    }
  }
}

// hf = relu(bn2(h)+skip), run-length pooled (batch sorted) + fused node count
__global__ void k_bn2_pool(const float* __restrict__ hfin, const float* __restrict__ h0,
                           const int* __restrict__ batch, const float* __restrict__ sc,
                           const float* __restrict__ sh, float* __restrict__ pool,
                           float* __restrict__ cntf, int N){
  int t=threadIdx.x, j=t&127, half=t>>7;
  int n0 = blockIdx.x*256 + half*128;
  float scv=sc[j], shv=sh[j];
  int curg=-1; float acc=0.f, cacc=0.f;
  for (int r=0;r<128;r++){
    int n=n0+r; if (n>=N) break;
    int g = batch[n];
    float v = fmaxf(hfin[(size_t)n*128+j]*scv+shv + h0[(size_t)n*128+j], 0.f);
    if (g!=curg){
      if (curg>=0){
        atomicAdd(&pool[curg*128+j], acc);
        if (j==0) atomicAdd(&cntf[curg], cacc);
      }
      curg=g; acc=0.f; cacc=0.f;
    }
    acc+=v; cacc+=1.f;
  }
  if (curg>=0){
    atomicAdd(&pool[curg*128+j], acc);
    if (j==0) atomicAdd(&cntf[curg], cacc);
  }
}

__global__ void k_head1(const float* __restrict__ pool, const float* __restrict__ cntf,
                        const float* __restrict__ W1cT, const float* __restrict__ b1,
                        float* __restrict__ t3, float* __restrict__ sum3, float* __restrict__ sq3){
  __shared__ float mean[128];
  int g=blockIdx.x, o=threadIdx.x;
  float inv = 1.0f/fmaxf(cntf[g],1.0f);
  mean[o] = pool[g*128+o]*inv;
  __syncthreads();
  float acc=0.f;
  for (int jj=0;jj<128;jj++) acc += mean[jj]*W1cT[jj*128+o];
  float v = acc + b1[o];
  t3[g*128+o]=v;
  atomicAdd(&sum3[o], v);
  atomicAdd(&sq3[o], v*v);
}

__global__ void k_head2(const float* __restrict__ t3, const float* __restrict__ sc,
                        const float* __restrict__ sh, const float* __restrict__ W2,
                        const float* __restrict__ b2, float* __restrict__ out){
  __shared__ float y[128];
  int g=blockIdx.x, o=threadIdx.x;
  float v = fmaxf(t3[g*128+o]*sc[o]+sh[o], 0.f);
  y[o]=v; __syncthreads();
  if (o<2){
    float acc=b2[o];
    for (int k=0;k<128;k++) acc += y[k]*W2[o*128+k];
    out[g*2+o]=acc;
  }
}

extern "C" void kernel_launch(void* const* d_in, const int* in_sizes, int n_in,
                              void* d_out, int out_size, void* d_ws, size_t ws_size,
                              hipStream_t stream){
  (void)n_in; (void)ws_size;
  const float* x    = (const float*)d_in[0];
  const int*   ei   = (const int*)d_in[1];
  const int*   batch= (const int*)d_in[2];
  const float* W_in = (const float*)d_in[3];
  const float* b_in = (const float*)d_in[4];
  const float* bn1_g= (const float*)d_in[5];
  const float* bn1_b= (const float*)d_in[6];
  const float* ggc  = (const float*)d_in[7];
  const float* wih  = (const float*)d_in[8];
  const float* whh  = (const float*)d_in[9];
  const float* bih  = (const float*)d_in[10];
  const float* bhh  = (const float*)d_in[11];
  const float* bn2_g= (const float*)d_in[12];
  const float* bn2_b= (const float*)d_in[13];
  const float* W1   = (const float*)d_in[14];
  const float* b1   = (const float*)d_in[15];
  const float* bn3_g= (const float*)d_in[16];
  const float* bn3_b= (const float*)d_in[17];
  const float* W2   = (const float*)d_in[18];
  const float* b2   = (const float*)d_in[19];
  float* out = (float*)d_out;

  int N = in_sizes[0]/128;
  int E = in_sizes[1]/2;
  int G = out_size/2;

  char* ws = (char*)d_ws;
  size_t off=0;
  auto alloc=[&](size_t bytes)->char*{
    char* p = ws+off; off = (off+bytes+255) & ~(size_t)255; return p;
  };
  float* buf0 = (float*)alloc((size_t)N*128*4);   // t -> s1/h1 -> s3/h3
  float* h0   = (float*)alloc((size_t)N*128*4);   // skip (persist)
  float* buf2 = (float*)alloc((size_t)N*128*4);   // s2/h2 -> s4/h4
  short* Bhi  = (short*)alloc((size_t)4*131072*2);
  short* Blo  = (short*)alloc((size_t)4*131072*2);
  float* Wq   = (float*)alloc((size_t)16384*4);
  float* W1cT = (float*)alloc((size_t)16384*4);
  int* rowptr = (int*)alloc((size_t)(N+1)*4);
  int* col    = (int*)alloc((size_t)E*4);
  int* bsum   = (int*)alloc((size_t)512*4);
  float* t3   = (float*)alloc((size_t)G*128*4);
  float* sc1 = (float*)alloc(512); float* sh1 = (float*)alloc(512);
  float* sc2 = (float*)alloc(512); float* sh2 = (float*)alloc(512);
  float* sc3 = (float*)alloc(512); float* sh3 = (float*)alloc(512);
  // --- zero region (contiguous) ---
  char* zstart = ws+off;
  int*   deg  = (int*)alloc((size_t)N*4);
  float* sumP1= (float*)alloc((size_t)64*128*4);
  float* sqP1 = (float*)alloc((size_t)64*128*4);
  float* sumP2= (float*)alloc((size_t)64*128*4);
  float* sqP2 = (float*)alloc((size_t)64*128*4);
  float* sum3 = (float*)alloc(512);
  float* sq3  = (float*)alloc(512);
  float* pool = (float*)alloc((size_t)G*128*4);
  float* cntf = (float*)alloc((size_t)G*4);
  char* zend = ws+off;
  int zwords = (int)((zend - zstart)/4);

  int nbScan  = (N+255)/256;     // 391 (<=512 for k_scan2)
  int gridN32 = (N+31)/32;       // 3125
  int gridAgg = (N*64+255)/256;

  k_zero<<<(zwords+255)/256,256,0,stream>>>((float*)zstart, zwords);
  k_prep<<<128,256,0,stream>>>(W_in, Wq, W1, W1cT);
  k_prepB<<<2048,256,0,stream>>>(ggc, wih, whh, Bhi, Blo);

  // CSR build
  k_hist<<<(E+255)/256,256,0,stream>>>(ei+E, deg, E);
  k_scan1<<<nbScan,256,0,stream>>>(deg, rowptr, bsum, N);
  k_scan2<<<1,512,0,stream>>>(bsum, nbScan, rowptr);
  k_scan3<<<nbScan,256,0,stream>>>(rowptr, bsum, N);
  k_fill<<<(E+255)/256,256,0,stream>>>(ei, deg, rowptr, col, E);

  // input GEMM + BN1
  k_gemm_in<<<gridN32,256,0,stream>>>(x, Wq, b_in, buf0, sumP1, sqP1, N);
  k_bn_fin<<<1,128,0,stream>>>(sumP1, sqP1, 64, 1.0f/(float)N, bn1_g, bn1_b, sc1, sh1);
  k_apply_bn1<<<(N*128/4+255)/256,256,0,stream>>>((const float4*)buf0, sc1, sh1, (float4*)h0, N*128/4);

  // 4 GRU steps: agg into s-buffer, MFMA GRU writes h in-place over s rows
  k_agg<<<gridAgg,256,0,stream>>>(h0,   buf0, rowptr, col, N);
  k_gru_mfma<<<gridN32,512,0,stream>>>(buf0, h0,   buf0, Bhi+0*131072, Blo+0*131072, bih, bhh, N, nullptr, nullptr);
  k_agg<<<gridAgg,256,0,stream>>>(buf0, buf2, rowptr, col, N);
  k_gru_mfma<<<gridN32,512,0,stream>>>(buf2, buf0, buf2, Bhi+1*131072, Blo+1*131072, bih, bhh, N, nullptr, nullptr);
  k_agg<<<gridAgg,256,0,stream>>>(buf2, buf0, rowptr, col, N);
  k_gru_mfma<<<gridN32,512,0,stream>>>(buf0, buf2, buf0, Bhi+2*131072, Blo+2*131072, bih, bhh, N, nullptr, nullptr);
  k_agg<<<gridAgg,256,0,stream>>>(buf0, buf2, rowptr, col, N);
  k_gru_mfma<<<gridN32,512,0,stream>>>(buf2, buf0, buf2, Bhi+3*131072, Blo+3*131072, bih, bhh, N, sumP2, sqP2);

  // BN2 + skip + pool (+count), head
  k_bn_fin<<<1,128,0,stream>>>(sumP2, sqP2, 64, 1.0f/(float)N, bn2_g, bn2_b, sc2, sh2);
  k_bn2_pool<<<(N+255)/256,256,0,stream>>>(buf2, h0, batch, sc2, sh2, pool, cntf, N);
  k_head1<<<G,128,0,stream>>>(pool, cntf, W1cT, b1, t3, sum3, sq3);
  k_bn_fin<<<1,128,0,stream>>>(sum3, sq3, 1, 1.0f/(float)G, bn3_g, bn3_b, sc3, sh3);
  k_head2<<<G,128,0,stream>>>(t3, sc3, sh3, W2, b2, out);
}